// Round 5
// baseline (8456.585 us; speedup 1.0000x reference)
//
#include <hip/hip_runtime.h>
#include <math.h>

#define Bq 16
#define Tq 32
#define Wq 128
#define Rq 4
#define Nq 512
#define Mq 128
#define XIDq 919
#define BTWq (Bq*Tq*Wq)

struct P {
  const float *X, *hs0, *mem0;
  const int *rst;
  const float *Wb,*bb,*Wff1,*bff1,*Wff2,*bff2,*Wta,*bta,*Wtb,*btb,*Wv,*bv,*Wr,*br,*Wxi,*bxi;
  float *out;
  float *memv,*memvT,*link;
};

__device__ __forceinline__ float sigf(float x){ return 1.f/(1.f+expf(-x)); }
__device__ __forceinline__ float oneplusf(float x){ return 1.f + log1pf(expf(x) + 1e-6f); }

__device__ __forceinline__ float wave_sum64(float v){
  #pragma unroll
  for (int m=32;m>=1;m>>=1) v += __shfl_xor(v, m, 64);
  return v;
}
__device__ __forceinline__ float wave_max64(float v){
  #pragma unroll
  for (int m=32;m>=1;m>>=1) v = fmaxf(v, __shfl_xor(v, m, 64));
  return v;
}
__device__ __forceinline__ float blk_sum(float v, float* s8){
  int w = threadIdx.x>>6;
  v = wave_sum64(v);
  if ((threadIdx.x&63)==0) s8[w] = v;
  __syncthreads();
  float r = s8[0]+s8[1]+s8[2]+s8[3]+s8[4]+s8[5]+s8[6]+s8[7];
  __syncthreads();
  return r;
}
__device__ __forceinline__ float blk_max(float v, float* s8){
  int w = threadIdx.x>>6;
  v = wave_max64(v);
  if ((threadIdx.x&63)==0) s8[w] = v;
  __syncthreads();
  float r = s8[0];
  #pragma unroll
  for (int q=1;q<8;q++) r = fmaxf(r, s8[q]);
  __syncthreads();
  return r;
}

// One block per batch. All 32 steps inside; only __syncthreads between phases.
// Small state lives in LDS for the whole sequence; link/memv/memvT in global,
// touched only by this block (single-CU locality, no cross-block coherence).
__global__ __launch_bounds__(512) void k_all(P p){
  const int b = blockIdx.x, tid = threadIdx.x;
  const int w = tid>>6, lane = tid&63;
  const int p4 = tid>>7, m = tid&127;   // (group, column) layout for matvecs

  __shared__ __align__(16) float rwl[Rq*Nq];
  __shared__ __align__(16) float fwl[Rq*Nq];
  __shared__ __align__(16) float bwl[Rq*Nq];
  __shared__ __align__(16) float rcl[Rq*Nq];
  __shared__ __align__(16) float xil[920];
  __shared__ __align__(16) float wcas[Nq];
  __shared__ __align__(16) float uarr[Nq];
  __shared__ __align__(16) float cpl[Nq];
  __shared__ __align__(16) float usage[Nq];
  __shared__ __align__(16) float wwl[Nq];
  __shared__ __align__(16) float precl[Nq];
  __shared__ __align__(16) float norms[Nq];
  __shared__ __align__(16) int   sidx[Nq];
  __shared__ __align__(16) float hsp[Wq];
  __shared__ __align__(16) float zl[Wq];
  __shared__ __align__(16) float xl[Wq];
  __shared__ __align__(16) float reads[Nq];
  __shared__ __align__(16) float acc4[4*Wq];
  __shared__ float s8[8];

  float* memv  = p.memv  + (size_t)b*Nq*Mq;
  float* memvT = p.memvT + (size_t)b*Nq*Mq;
  float* link  = p.link  + (size_t)b*Nq*Nq;

  // ---------- init (block-local, every call) ----------
  {
    float4* L = (float4*)link;
    float4 z4 = make_float4(0.f,0.f,0.f,0.f);
    for (int i=tid; i<Nq*Nq/4; i+=512) L[i] = z4;
    for (int nn=0; nn<128; nn++){
      int n = p4*128 + nn;
      float v = p.mem0[(size_t)b*Nq*Mq + (size_t)n*Mq + m];
      memv[(size_t)n*Mq + m] = v;
      memvT[(size_t)m*Nq + n] = v;
    }
    for (int i=tid; i<Rq*Nq; i+=512) rwl[i]=0.f;
    usage[tid]=0.f; precl[tid]=0.f; wwl[tid]=0.f;
    if (tid<Wq) hsp[tid] = p.hs0[b*Wq+tid];
    __syncthreads();
    {
      int n = tid;
      float s=0.f;
      #pragma unroll 8
      for (int mm=0;mm<Mq;mm++){ float v = memvT[(size_t)mm*Nq+n]; s += v*v; }
      norms[n] = sqrtf(s);
    }
    __syncthreads();
  }

  float wsum = 0.f;
  for (int t=0; t<=Tq; t++){
    // ---- P1: rw(t-1) = modes-combine(bw, rca, fw), all from LDS ----
    if (t>0){
      int n = tid;
      #pragma unroll
      for (int r=0;r<Rq;r++){
        float m0=xil[904+r*3], m1=xil[905+r*3], m2=xil[906+r*3];
        float mm2=fmaxf(m0,fmaxf(m1,m2));
        float e0=expf(m0-mm2), e1=expf(m1-mm2), e2=expf(m2-mm2);
        float es=e0+e1+e2;
        rwl[r*Nq+n] = (e0*bwl[r*Nq+n] + e1*rcl[r*Nq+n] + e2*fwl[r*Nq+n])/es;
      }
    }
    __syncthreads();
    // ---- P2: reads(t-1) = rw @ memv (coalesced over m) ----
    if (t>0){
      const float* rr = rwl + p4*Nq;
      float a0=0.f,a1=0.f,a2=0.f,a3=0.f;
      for (int n=0;n<Nq;n+=4){
        a0 += rr[n+0]*memv[(size_t)(n+0)*Mq+m];
        a1 += rr[n+1]*memv[(size_t)(n+1)*Mq+m];
        a2 += rr[n+2]*memv[(size_t)(n+2)*Mq+m];
        a3 += rr[n+3]*memv[(size_t)(n+3)*Mq+m];
      }
      reads[p4*Wq+m] = (a0+a1)+(a2+a3);
    } else {
      reads[tid] = 0.f;
    }
    __syncthreads();
    // ---- P3: y(t-1) = hs@Wv + reads@Wr + bv + br ----
    if (t>0){
      float acc=0.f;
      #pragma unroll 4
      for (int ii=0;ii<160;ii++){
        int i = p4*160 + ii;
        acc += (i<Wq) ? hsp[i]*p.Wv[(size_t)i*Wq+m]
                      : reads[i-Wq]*p.Wr[(size_t)(i-Wq)*Wq+m];
      }
      acc4[p4*Wq+m] = acc;
      __syncthreads();
      if (tid<Wq){
        float y = acc4[tid]+acc4[Wq+tid]+acc4[2*Wq+tid]+acc4[3*Wq+tid]
                + p.bv[tid]+p.br[tid];
        p.out[((size_t)b*Tq + (t-1))*Wq + tid] = y;
      }
      __syncthreads();
    }
    if (t==Tq) break;

    float keep = 1.f - (float)p.rst[b*Tq + t];
    // ---- P4: z = silu([x | reads | keep*hs] @ Wb + bb) ----
    if (tid<Wq) xl[tid] = p.X[((size_t)b*Tq + t)*Wq + tid];
    __syncthreads();
    {
      float acc=0.f;
      #pragma unroll 4
      for (int ii=0;ii<192;ii++){
        int i = p4*192 + ii;
        float iv = (i<Wq)? xl[i] : (i<Wq+Nq)? reads[i-Wq] : keep*hsp[i-Wq-Nq];
        acc += iv * p.Wb[(size_t)i*Wq + m];
      }
      acc4[p4*Wq+m] = acc;
    }
    __syncthreads();
    if (tid<Wq){
      float a = acc4[tid]+acc4[Wq+tid]+acc4[2*Wq+tid]+acc4[3*Wq+tid] + p.bb[tid];
      zl[tid] = a*sigf(a);
    }
    __syncthreads();
    // ---- P5: hs = ff1*(1-ti)+ti*ff2 ----
    {
      const float* Wg = (p4==0)? p.Wff1 : (p4==1)? p.Wff2 : (p4==2)? p.Wta : p.Wtb;
      float acc=0.f;
      #pragma unroll 4
      for (int i=0;i<Wq;i++) acc += zl[i]*Wg[(size_t)i*Wq+m];
      acc4[p4*Wq+m] = acc;
    }
    __syncthreads();
    if (tid<Wq){
      float a1=acc4[tid]+p.bff1[tid], a2=acc4[Wq+tid]+p.bff2[tid];
      float aa=acc4[2*Wq+tid]+p.bta[tid], ab=acc4[3*Wq+tid]+p.btb[tid];
      float ti = sigf(aa*(float)t + ab);
      float h = a1*(1.f-ti) + ti*a2;
      hsp[tid] = h;
      p.out[BTWq + ((size_t)b*Tq + t)*Wq + tid] = h;
    }
    __syncthreads();
    // ---- P6: xi = hs @ Wxi + bxi (coalesced over f) ----
    {
      int f = tid;
      float acc = p.bxi[f];
      #pragma unroll 4
      for (int i=0;i<Wq;i++) acc += hsp[i]*p.Wxi[(size_t)i*XIDq + f];
      xil[f] = acc;
      int f2 = tid + 512;
      if (f2 < XIDq){
        float a2 = p.bxi[f2];
        #pragma unroll 4
        for (int i=0;i<Wq;i++) a2 += hsp[i]*p.Wxi[(size_t)i*XIDq + f2];
        xil[f2] = a2;
      }
    }
    __syncthreads();
    // ---- P7: addr — wca, usage, rank-sort, cumprod, alloc, ww ----
    {
      float kk = (tid<Wq)? xil[512+tid]*xil[512+tid] : 0.f;
      float kn = sqrtf(blk_sum(kk, s8));
      int n = tid;
      float d=0.f;
      #pragma unroll 8
      for (int mm=0;mm<Mq;mm++) d += xil[512+mm]*memvT[(size_t)mm*Nq+n];
      float mn = norms[n];
      float sim = (keep*d)/(kn*(keep*mn) + 1e-6f);
      float wstr = oneplusf(xil[916]);
      float v = wstr*sim;
      float mx = blk_max(v, s8);
      float e = expf(v-mx);
      float se = blk_sum(e, s8);
      wcas[n] = e/se;
      float ret = 1.f;
      #pragma unroll
      for (int r=0;r<Rq;r++) ret *= 1.f - sigf(xil[896+r])*rwl[r*Nq+n];
      float uo = usage[n], pw = wwl[n];
      float u = (uo + pw - uo*pw)*ret;
      usage[n] = u; uarr[n] = u;
      __syncthreads();
      // stable ascending rank: #{j: u_j<u_i} + #{j<i: u_j==u_i}
      int rank = 0;
      const float4* u4 = (const float4*)uarr;
      #pragma unroll 8
      for (int jj=0;jj<128;jj++){
        float4 vv = u4[jj]; int j0 = jj*4;
        rank += (vv.x<u)||(vv.x==u&&(j0+0)<n);
        rank += (vv.y<u)||(vv.y==u&&(j0+1)<n);
        rank += (vv.z<u)||(vv.z==u&&(j0+2)<n);
        rank += (vv.w<u)||(vv.w==u&&(j0+3)<n);
      }
      sidx[rank] = n;
      __syncthreads();
      int si = sidx[n];
      float sv = uarr[si];
      float x = sv;
      #pragma unroll
      for (int dd=1;dd<64;dd<<=1){
        float pr = __shfl_up(x, dd, 64);
        if (lane >= dd) x *= pr;
      }
      if (lane==63) s8[w] = x;
      __syncthreads();
      float woff = 1.f;
      #pragma unroll
      for (int q=0;q<8;q++) if (q<w) woff *= s8[q];
      x *= woff;
      cpl[n] = x;
      __syncthreads();
      float alloc = (1.f - u)*cpl[si];   // reference's cp[si[k]] indexing
      float ag = sigf(xil[917]), wg = sigf(xil[918]);
      float wwv = wg*(ag*alloc + (1.f-ag)*wcas[n]);
      wwl[n] = wwv;
      wsum = blk_sum(wwv, s8);           // internal syncs order wwl writes
    }
    // ---- P8: link update + fw/bw (prec old), then prec update ----
    {
      int c0 = lane*8;
      float ww8[8], pc8[8], pr8[Rq][8];
      *(float4*)&ww8[0] = *(const float4*)&wwl[c0];
      *(float4*)&ww8[4] = *(const float4*)&wwl[c0+4];
      *(float4*)&pc8[0] = *(const float4*)&precl[c0];
      *(float4*)&pc8[4] = *(const float4*)&precl[c0+4];
      #pragma unroll
      for (int r=0;r<Rq;r++){
        *(float4*)&pr8[r][0] = *(const float4*)&rwl[r*Nq+c0];
        *(float4*)&pr8[r][4] = *(const float4*)&rwl[r*Nq+c0+4];
      }
      float fa[Rq][8];
      #pragma unroll
      for (int r=0;r<Rq;r++)
        #pragma unroll
        for (int q=0;q<8;q++) fa[r][q]=0.f;
      for (int g=0; g<8; g++){
        for (int rr=0; rr<8; rr++){
          int n = g*64 + w*8 + rr;
          float wwn = wwl[n];
          float prn[Rq];
          #pragma unroll
          for (int r=0;r<Rq;r++) prn[r] = rwl[r*Nq+n];
          size_t row = (size_t)n*Nq;
          float4 La = *(const float4*)(link + row + c0);
          float4 Lb = *(const float4*)(link + row + c0 + 4);
          float vv[8] = {La.x,La.y,La.z,La.w,Lb.x,Lb.y,Lb.z,Lb.w};
          float bwp[Rq] = {0.f,0.f,0.f,0.f};
          #pragma unroll
          for (int q=0;q<8;q++){
            float nv = (1.f - wwn - ww8[q])*vv[q] + wwn*pc8[q];
            if (c0 + q == n) nv = 0.f;
            vv[q] = nv;
            #pragma unroll
            for (int r=0;r<Rq;r++){ fa[r][q] += prn[r]*nv; bwp[r] += pr8[r][q]*nv; }
          }
          *(float4*)(link + row + c0)     = make_float4(vv[0],vv[1],vv[2],vv[3]);
          *(float4*)(link + row + c0 + 4) = make_float4(vv[4],vv[5],vv[6],vv[7]);
          #pragma unroll
          for (int mm=1;mm<64;mm<<=1)
            #pragma unroll
            for (int r=0;r<Rq;r++) bwp[r] += __shfl_xor(bwp[r], mm, 64);
          if (lane==0){
            #pragma unroll
            for (int r=0;r<Rq;r++) bwl[r*Nq+n] = bwp[r];
          }
        }
      }
      __syncthreads();
      // fw: deterministic 8-round wave-serialized accumulation
      for (int k=0;k<8;k++){
        if (w==k){
          #pragma unroll
          for (int r=0;r<Rq;r++)
            #pragma unroll
            for (int q=0;q<8;q++){
              if (k==0) fwl[r*Nq+c0+q]  = fa[r][q];
              else      fwl[r*Nq+c0+q] += fa[r][q];
            }
        }
        __syncthreads();
      }
      precl[tid] = (1.f - wsum)*precl[tid] + wwl[tid];
      __syncthreads();
    }
    // ---- P9: memory write (coalesced over m) + memvT maintenance ----
    {
      float er  = sigf(xil[768+m]);
      float wvv = xil[640+m];
      for (int nn=0;nn<128;nn++){
        int n = p4*128 + nn;
        float wwn = wwl[n];
        float mv = memv[(size_t)n*Mq + m];
        mv = mv*keep*(1.f - wwn*er) + wwn*wvv;
        memv[(size_t)n*Mq + m] = mv;
        memvT[(size_t)m*Nq + n] = mv;
      }
    }
    __syncthreads();
    // ---- P10: new norms + rca (single memvT pass, 4 keys) ----
    {
      float kn4[Rq], rstr[Rq];
      #pragma unroll
      for (int r=0;r<Rq;r++){
        float kk = (tid<Wq)? xil[r*Wq+tid]*xil[r*Wq+tid] : 0.f;
        kn4[r] = sqrtf(blk_sum(kk, s8));
        rstr[r] = oneplusf(xil[900+r]);
      }
      int n = tid;
      float d0=0.f,d1=0.f,d2=0.f,d3=0.f,s=0.f;
      #pragma unroll 4
      for (int mm=0;mm<Mq;mm++){
        float v = memvT[(size_t)mm*Nq + n];
        s  += v*v;
        d0 += xil[mm]*v;       d1 += xil[Wq+mm]*v;
        d2 += xil[2*Wq+mm]*v;  d3 += xil[3*Wq+mm]*v;
      }
      float mn = sqrtf(s);
      norms[n] = mn;
      float dd[4] = {d0,d1,d2,d3};
      #pragma unroll
      for (int r=0;r<Rq;r++){
        float v = rstr[r]*(dd[r]/(kn4[r]*mn + 1e-6f));
        float mx = blk_max(v, s8);
        float e = expf(v - mx);
        float se = blk_sum(e, s8);
        rcl[r*Nq+n] = e/se;
      }
    }
    __syncthreads();
  } // t loop
}

extern "C" void kernel_launch(void* const* d_in, const int* in_sizes, int n_in,
                              void* d_out, int out_size, void* d_ws, size_t ws_size,
                              hipStream_t stream){
  (void)in_sizes; (void)n_in; (void)out_size; (void)ws_size;
  P p;
  p.X    = (const float*)d_in[0];
  p.hs0  = (const float*)d_in[1];
  p.mem0 = (const float*)d_in[2];
  p.rst  = (const int*)d_in[3];
  p.Wb   = (const float*)d_in[4];  p.bb   = (const float*)d_in[5];
  p.Wff1 = (const float*)d_in[6];  p.bff1 = (const float*)d_in[7];
  p.Wff2 = (const float*)d_in[8];  p.bff2 = (const float*)d_in[9];
  p.Wta  = (const float*)d_in[10]; p.bta  = (const float*)d_in[11];
  p.Wtb  = (const float*)d_in[12]; p.btb  = (const float*)d_in[13];
  p.Wv   = (const float*)d_in[14]; p.bv   = (const float*)d_in[15];
  p.Wr   = (const float*)d_in[16]; p.br   = (const float*)d_in[17];
  p.Wxi  = (const float*)d_in[18]; p.bxi  = (const float*)d_in[19];
  p.out  = (float*)d_out;
  float* ws = (float*)d_ws;
  size_t o = 0;
  p.memv  = ws + o; o += (size_t)Bq*Nq*Mq;   // 1,048,576
  p.memvT = ws + o; o += (size_t)Bq*Nq*Mq;   // 1,048,576
  p.link  = ws + o; o += (size_t)Bq*Nq*Nq;   // 4,194,304

  hipLaunchKernelGGL(k_all, dim3(Bq), dim3(512), 0, stream, p);
}

// Round 6
// 4327.127 us; speedup vs baseline: 1.9543x; 1.9543x over previous
//
#include <hip/hip_runtime.h>
#include <math.h>

#define Bq 16
#define Tq 32
#define Wq 128
#define Rq 4
#define Nq 512
#define Mq 128
#define DINq 768
#define XIDq 919
#define BTWq (Bq*Tq*Wq)

// per-team payload arena (floats)
#define TSTRIDE 24576
#define TF_FW    0        // [8][4*512]
#define TF_BW    16384    // [4*512]
#define TF_RW    18432    // [4*512]
#define TF_WW    20480    // [512]
#define TF_PREC  20992    // [2][512] parity
#define TF_XI    22016    // [920]
#define TF_Z     22944    // [128]
#define TF_HS    23072    // [128]
#define TF_READS 23200    // [512]
#define TF_CNT   23712    // barrier counter (as unsigned)

struct P {
  const float *X, *hs0, *mem0;
  const int *rst;
  const float *Wb,*bb,*Wff1,*bff1,*Wff2,*bff2,*Wta,*bta,*Wtb,*btb,*Wv,*bv,*Wr,*br,*Wxi,*bxi;
  float *out;
  float *link,*rdh,*memv,*teams;
  float *WbT,*Wff1T,*Wff2T,*WtaT,*WtbT,*WvT,*WrT,*WxiT;
};

__device__ __forceinline__ float dot4(float4 a, float4 b){
  return a.x*b.x + a.y*b.y + a.z*b.z + a.w*b.w;
}
__device__ __forceinline__ float sigf(float x){ return 1.f/(1.f+expf(-x)); }
__device__ __forceinline__ float oneplusf(float x){ return 1.f + log1pf(expf(x) + 1e-6f); }

// coherent (agent-scope) payload access: per-access, no cache-wide maintenance
__device__ __forceinline__ void pst(float* p, float v){
  __hip_atomic_store(p, v, __ATOMIC_RELAXED, __HIP_MEMORY_SCOPE_AGENT);
}
__device__ __forceinline__ float pld(float* p){
  return __hip_atomic_load(p, __ATOMIC_RELAXED, __HIP_MEMORY_SCOPE_AGENT);
}

__device__ __forceinline__ void team_bar(unsigned* cnt, unsigned& gen){
  __syncthreads();                       // drains vmcnt: payload stores complete
  gen += 9;
  if (threadIdx.x==0){
    __hip_atomic_fetch_add(cnt, 1u, __ATOMIC_ACQ_REL, __HIP_MEMORY_SCOPE_AGENT);
    while (__hip_atomic_load(cnt, __ATOMIC_ACQUIRE, __HIP_MEMORY_SCOPE_AGENT) < gen)
      __builtin_amdgcn_s_sleep(1);
  }
  __syncthreads();
}

__device__ __forceinline__ float wave_sum64(float v){
  #pragma unroll
  for (int m=32;m>=1;m>>=1) v += __shfl_xor(v, m, 64);
  return v;
}
__device__ __forceinline__ float wave_max64(float v){
  #pragma unroll
  for (int m=32;m>=1;m>>=1) v = fmaxf(v, __shfl_xor(v, m, 64));
  return v;
}
__device__ __forceinline__ float blk_sum(float v, float* s8){
  int w = threadIdx.x>>6;
  v = wave_sum64(v);
  if ((threadIdx.x&63)==0) s8[w] = v;
  __syncthreads();
  float r = s8[0]+s8[1]+s8[2]+s8[3]+s8[4]+s8[5]+s8[6]+s8[7];
  __syncthreads();
  return r;
}
__device__ __forceinline__ float blk_max(float v, float* s8){
  int w = threadIdx.x>>6;
  v = wave_max64(v);
  if ((threadIdx.x&63)==0) s8[w] = v;
  __syncthreads();
  float r = s8[0];
  #pragma unroll
  for (int q=1;q<8;q++) r = fmaxf(r, s8[q]);
  __syncthreads();
  return r;
}

// ---------- k_init: weight transposes + zero team arenas ----------
__global__ __launch_bounds__(256) void k_init(P p){
  int bid=blockIdx.x, tid=threadIdx.x;
  if (bid<8){ int idx=bid*256+tid, st=8*256;
    for (int k=idx;k<DINq*Wq;k+=st){ int j=k/DINq,i=k%DINq; p.WbT[k]=p.Wb[i*Wq+j]; }
  } else if (bid<10){ int idx=(bid-8)*256+tid, st=2*256;
    for (int k=idx;k<Wq*Wq;k+=st){ int j=k/Wq,i=k%Wq; p.Wff1T[k]=p.Wff1[i*Wq+j]; }
  } else if (bid<12){ int idx=(bid-10)*256+tid, st=2*256;
    for (int k=idx;k<Wq*Wq;k+=st){ int j=k/Wq,i=k%Wq; p.Wff2T[k]=p.Wff2[i*Wq+j]; }
  } else if (bid<14){ int idx=(bid-12)*256+tid, st=2*256;
    for (int k=idx;k<Wq*Wq;k+=st){ int j=k/Wq,i=k%Wq; p.WtaT[k]=p.Wta[i*Wq+j]; }
  } else if (bid<16){ int idx=(bid-14)*256+tid, st=2*256;
    for (int k=idx;k<Wq*Wq;k+=st){ int j=k/Wq,i=k%Wq; p.WtbT[k]=p.Wtb[i*Wq+j]; }
  } else if (bid<18){ int idx=(bid-16)*256+tid, st=2*256;
    for (int k=idx;k<Wq*Wq;k+=st){ int j=k/Wq,i=k%Wq; p.WvT[k]=p.Wv[i*Wq+j]; }
  } else if (bid<22){ int idx=(bid-18)*256+tid, st=4*256;
    for (int k=idx;k<Rq*Wq*Wq;k+=st){ int j=k/(Rq*Wq),i=k%(Rq*Wq); p.WrT[k]=p.Wr[i*Wq+j]; }
  } else if (bid<30){ int idx=(bid-22)*256+tid, st=8*256;
    for (int k=idx;k<XIDq*Wq;k+=st){ int f=k/Wq,i=k%Wq; p.WxiT[k]=p.Wxi[i*XIDq+f]; }
  } else if (bid<38){ int idx=(bid-30)*256+tid, st=8*256;
    for (int k=idx;k<16*TSTRIDE;k+=st) p.teams[k]=0.f;
  }
}

// ---------- k_run: 16 teams x 9 blocks, whole scan ----------
__global__ __launch_bounds__(512) void k_run(P p){
  const int tid=threadIdx.x;
  const int team=blockIdx.x&15, mem=blockIdx.x>>4;  // mem 0..8
  const int b=team;
  float* T = p.teams + (size_t)team*TSTRIDE;
  unsigned* cnt = (unsigned*)(T + TF_CNT);
  unsigned gen = 0;

  __shared__ __align__(16) float rwl[Rq*Nq];
  __shared__ __align__(16) float rcl[Rq*Nq];
  __shared__ __align__(16) float xil[XIDq+9];
  __shared__ __align__(16) float inv[DINq];
  __shared__ __align__(16) float zll[Wq];
  __shared__ __align__(16) float hsl[Wq];
  __shared__ __align__(16) float wwl[Nq];
  __shared__ __align__(16) float precl[Nq];
  __shared__ __align__(16) float usage[Nq];
  __shared__ __align__(16) float wca[Nq];
  __shared__ __align__(16) float uarr[Nq];
  __shared__ __align__(16) float cpl[Nq];
  __shared__ __align__(16) float norms[Nq];
  __shared__ __align__(16) int   sidx[Nq];
  __shared__ __align__(16) float erl[Wq], wvl[Wq];
  __shared__ __align__(16) float fwacc[Rq*Nq];
  __shared__ float gacc[64];
  __shared__ float s8[8];

  // ---- init ----
  if (mem==0){
    for (int i=tid;i<Nq*Mq;i+=512) p.memv[(size_t)b*Nq*Mq+i] = p.mem0[(size_t)b*Nq*Mq+i];
    for (int i=tid;i<Rq*Nq;i+=512){ rwl[i]=0.f; rcl[i]=0.f; }
    usage[tid]=0.f; precl[tid]=0.f; wwl[tid]=0.f;
    if (tid<Wq) pst(T+TF_HS+tid, p.hs0[b*Wq+tid]);
    __syncthreads();
    { int n=tid;
      const float4* mr=(const float4*)(p.memv+((size_t)b*Nq+n)*Mq);
      float s=0.f;
      #pragma unroll 8
      for (int c=0;c<32;c++) s+=dot4(mr[c],mr[c]);
      norms[n]=sqrtf(s);
    }
  } else {
    size_t base = ((size_t)b*Nq + (size_t)(mem-1)*64)*Nq;
    float4* L = (float4*)(p.link + base);
    float4 z4 = make_float4(0.f,0.f,0.f,0.f);
    for (int i=tid;i<64*Nq/4;i+=512) L[i]=z4;
  }
  team_bar(cnt, gen);  // B0

  for (int t=0; t<=Tq; t++){
    // ---- ph1 (alpha): rw(t-1) combine + reads(t-1) ----
    if (mem==0){
      if (t>0){
        int n=tid;
        #pragma unroll
        for (int r=0;r<Rq;r++){
          float m0=xil[904+r*3], m1=xil[905+r*3], m2=xil[906+r*3];
          float mm=fmaxf(m0,fmaxf(m1,m2));
          float e0=expf(m0-mm), e1=expf(m1-mm), e2=expf(m2-mm);
          float es=e0+e1+e2;
          float fwv=0.f;
          #pragma unroll
          for (int g=0;g<8;g++) fwv += pld(T+TF_FW+g*2048+r*Nq+n);
          float bwv = pld(T+TF_BW+r*Nq+n);
          float rwv = (e0*bwv + e1*rcl[r*Nq+n] + e2*fwv)/es;
          rwl[r*Nq+n]=rwv;
          pst(T+TF_RW+r*Nq+n, rwv);
        }
        __syncthreads();
        int p4=tid>>7, m=tid&127;
        const float* rr_ = rwl + p4*Nq;
        const float* mb = p.memv + (size_t)b*Nq*Mq + m;
        float a0=0.f,a1=0.f,a2=0.f,a3=0.f;
        for (int n=0;n<Nq;n+=4){
          a0+=rr_[n+0]*mb[(size_t)(n+0)*Mq];
          a1+=rr_[n+1]*mb[(size_t)(n+1)*Mq];
          a2+=rr_[n+2]*mb[(size_t)(n+2)*Mq];
          a3+=rr_[n+3]*mb[(size_t)(n+3)*Mq];
        }
        float a=(a0+a1)+(a2+a3);
        pst(T+TF_READS+tid, a);
        p.rdh[((size_t)b*Tq + (t-1))*Nq + tid] = a;
      } else {
        for (int i=tid;i<Rq*Nq;i+=512) pst(T+TF_RW+i, 0.f);
        pst(T+TF_READS+tid, 0.f);
      }
    }
    team_bar(cnt, gen);  // B1
    if (t==Tq) break;

    float keep = 1.f - (float)p.rst[b*Tq + t];
    // ---- ph2 (all): z-slice ----
    for (int i=tid;i<DINq;i+=512){
      float v;
      if (i<Wq) v = p.X[((size_t)b*Tq+t)*Wq + i];
      else if (i<Wq+Nq) v = pld(T+TF_READS+i-Wq);
      else v = keep*pld(T+TF_HS+i-Wq-Nq);
      inv[i]=v;
    }
    __syncthreads();
    {
      int jj=tid>>5, q=tid&31;
      int j0=mem*15, jn=(128-j0<15)?(128-j0):15;
      if (jj<jn){
        int j=j0+jj;
        const float4* w4=(const float4*)(p.WbT+(size_t)j*DINq);
        const float4* i4=(const float4*)inv;
        float a=0.f;
        #pragma unroll
        for (int kk=0;kk<6;kk++) a+=dot4(w4[q*6+kk], i4[q*6+kk]);
        #pragma unroll
        for (int m=1;m<32;m<<=1) a+=__shfl_xor(a,m,32);
        if (q==0){ a+=p.bb[j]; pst(T+TF_Z+j, a*sigf(a)); }
      }
    }
    team_bar(cnt, gen);  // B2
    // ---- ph3 (all): hs-slice ----
    if (tid<Wq) zll[tid]=pld(T+TF_Z+tid);
    __syncthreads();
    {
      int jj=tid>>5, gate=(tid>>3)&3, q=tid&7;
      int j0=mem*15, jn=(128-j0<15)?(128-j0):15;
      float a=0.f;
      if (jj<jn){
        int j=j0+jj;
        const float* Wg = (gate==0)?p.Wff1T:(gate==1)?p.Wff2T:(gate==2)?p.WtaT:p.WtbT;
        const float4* w4=(const float4*)(Wg+(size_t)j*Wq);
        const float4* z4=(const float4*)zll;
        #pragma unroll
        for (int kk=0;kk<4;kk++) a+=dot4(w4[q*4+kk], z4[q*4+kk]);
        a+=__shfl_xor(a,1,8); a+=__shfl_xor(a,2,8); a+=__shfl_xor(a,4,8);
      }
      if (q==0) gacc[jj*4+gate]=a;
      __syncthreads();
      if (tid<16 && tid<jn){
        int j=j0+tid;
        float a1=gacc[tid*4+0]+p.bff1[j], a2=gacc[tid*4+1]+p.bff2[j];
        float aa=gacc[tid*4+2]+p.bta[j],  ab=gacc[tid*4+3]+p.btb[j];
        float ti=sigf(aa*(float)t+ab);
        float h=a1*(1.f-ti)+ti*a2;
        pst(T+TF_HS+j, h);
        p.out[BTWq + ((size_t)b*Tq+t)*Wq + j] = h;
      }
    }
    team_bar(cnt, gen);  // B3
    // ---- ph4 (all): xi-slice ----
    if (tid<Wq) hsl[tid]=pld(T+TF_HS+tid);
    __syncthreads();
    {
      int ff=tid>>2, q=tid&3;
      int f0=mem*103, fn=(XIDq-f0<103)?(XIDq-f0):103;
      if (ff<fn){
        int f=f0+ff;
        const float4* w4=(const float4*)(p.WxiT+(size_t)f*Wq);
        const float4* h4=(const float4*)hsl;
        float a=0.f;
        #pragma unroll
        for (int kk=0;kk<8;kk++) a+=dot4(w4[q*8+kk], h4[q*8+kk]);
        a+=__shfl_xor(a,1,4); a+=__shfl_xor(a,2,4);
        if (q==0) pst(T+TF_XI+f, a+p.bxi[f]);
      }
    }
    team_bar(cnt, gen);  // B4
    // ---- ph5: alpha addr ; links prefetch rw/prec_old ----
    if (mem==0){
      for (int i=tid;i<XIDq;i+=512) xil[i]=pld(T+TF_XI+i);
      __syncthreads();
      float kk2 = (tid<Wq)? xil[512+tid]*xil[512+tid] : 0.f;
      float kn = sqrtf(blk_sum(kk2, s8));
      int n=tid;
      const float4* k4=(const float4*)(xil+512);
      const float4* mr=(const float4*)(p.memv+((size_t)b*Nq+n)*Mq);
      float d=0.f;
      #pragma unroll 8
      for (int c=0;c<32;c++) d+=dot4(k4[c],mr[c]);
      float mn=norms[n];
      float sim=(keep*d)/(kn*(keep*mn)+1e-6f);
      float wstr=oneplusf(xil[916]);
      float v=wstr*sim;
      float mx=blk_max(v,s8);
      float e=expf(v-mx);
      float se=blk_sum(e,s8);
      wca[n]=e/se;
      float ret=1.f;
      #pragma unroll
      for (int r=0;r<Rq;r++) ret *= 1.f - sigf(xil[896+r])*rwl[r*Nq+n];
      float uo=usage[n], pw=wwl[n];
      float u=(uo+pw-uo*pw)*ret;
      usage[n]=u; uarr[n]=u;
      __syncthreads();
      int rank=0;
      const float4* u4=(const float4*)uarr;
      #pragma unroll 8
      for (int jj=0;jj<128;jj++){
        float4 vv=u4[jj]; int j0=jj*4;
        rank += (vv.x<u)||(vv.x==u&&(j0+0)<n);
        rank += (vv.y<u)||(vv.y==u&&(j0+1)<n);
        rank += (vv.z<u)||(vv.z==u&&(j0+2)<n);
        rank += (vv.w<u)||(vv.w==u&&(j0+3)<n);
      }
      sidx[rank]=n;
      __syncthreads();
      int si=sidx[n];
      float sv=uarr[si];
      int w=tid>>6, l=tid&63;
      float x=sv;
      #pragma unroll
      for (int dd=1;dd<64;dd<<=1){
        float pr=__shfl_up(x,dd,64);
        if (l>=dd) x*=pr;
      }
      if (l==63) s8[w]=x;
      __syncthreads();
      float woff=1.f;
      #pragma unroll
      for (int q=0;q<8;q++) if (q<w) woff*=s8[q];
      x*=woff;
      cpl[n]=x;
      __syncthreads();
      float alloc=(1.f-u)*cpl[si];        // reference's cp[si[k]] indexing
      float ag=sigf(xil[917]), wg=sigf(xil[918]);
      float wwv=wg*(ag*alloc+(1.f-ag)*wca[n]);
      wwl[n]=wwv;
      pst(T+TF_WW+n, wwv);
      float wsum=blk_sum(wwv,s8);
      float pn=(1.f-wsum)*precl[n]+wwv;
      precl[n]=pn;
      pst(T+TF_PREC+(t&1)*Nq+n, pn);
    } else {
      for (int i=tid;i<Rq*Nq;i+=512) rwl[i]=pld(T+TF_RW+i);
      precl[tid]=pld(T+TF_PREC+((t&1)^1)*Nq+tid);
    }
    team_bar(cnt, gen);  // B5
    // ---- ph6 (links): link update + fw/bw ; ph7 (alpha): mem + norms + rca ----
    if (mem>0){
      wwl[tid]=pld(T+TF_WW+tid);
      for (int i=tid;i<Rq*Nq;i+=512) fwacc[i]=0.f;
      __syncthreads();
      int g=mem-1;
      int w=tid>>6, l=tid&63, c0=l*8;
      float ww8[8], pc8[8], pr8[Rq][8];
      *(float4*)&ww8[0]=*(const float4*)&wwl[c0];   *(float4*)&ww8[4]=*(const float4*)&wwl[c0+4];
      *(float4*)&pc8[0]=*(const float4*)&precl[c0]; *(float4*)&pc8[4]=*(const float4*)&precl[c0+4];
      #pragma unroll
      for (int r=0;r<Rq;r++){
        *(float4*)&pr8[r][0]=*(const float4*)&rwl[r*Nq+c0];
        *(float4*)&pr8[r][4]=*(const float4*)&rwl[r*Nq+c0+4];
      }
      float fa[Rq][8];
      #pragma unroll
      for (int r=0;r<Rq;r++)
        #pragma unroll
        for (int q=0;q<8;q++) fa[r][q]=0.f;
      for (int rr=0;rr<8;rr++){
        int n = g*64 + w*8 + rr;
        float wwn = wwl[n];
        float prn[Rq];
        #pragma unroll
        for (int r=0;r<Rq;r++) prn[r]=rwl[r*Nq+n];
        size_t row = ((size_t)b*Nq+n)*Nq;
        float4 La=*(const float4*)(p.link+row+c0);
        float4 Lb=*(const float4*)(p.link+row+c0+4);
        float vv[8]={La.x,La.y,La.z,La.w,Lb.x,Lb.y,Lb.z,Lb.w};
        float bwp[Rq]={0.f,0.f,0.f,0.f};
        #pragma unroll
        for (int q=0;q<8;q++){
          float nv=(1.f-wwn-ww8[q])*vv[q]+wwn*pc8[q];
          if (c0+q==n) nv=0.f;
          vv[q]=nv;
          #pragma unroll
          for (int r=0;r<Rq;r++){ fa[r][q]+=prn[r]*nv; bwp[r]+=pr8[r][q]*nv; }
        }
        *(float4*)(p.link+row+c0)   = make_float4(vv[0],vv[1],vv[2],vv[3]);
        *(float4*)(p.link+row+c0+4) = make_float4(vv[4],vv[5],vv[6],vv[7]);
        #pragma unroll
        for (int mm=1;mm<64;mm<<=1)
          #pragma unroll
          for (int r=0;r<Rq;r++) bwp[r]+=__shfl_xor(bwp[r],mm,64);
        if (l==0){
          #pragma unroll
          for (int r=0;r<Rq;r++) pst(T+TF_BW+r*Nq+n, bwp[r]);
        }
      }
      #pragma unroll
      for (int r=0;r<Rq;r++)
        #pragma unroll
        for (int q=0;q<8;q++) atomicAdd(&fwacc[r*Nq+c0+q], fa[r][q]);
      __syncthreads();
      for (int i=tid;i<Rq*Nq;i+=512) pst(T+TF_FW+g*2048+i, fwacc[i]);
    } else {
      if (tid<Wq){ erl[tid]=sigf(xil[768+tid]); wvl[tid]=xil[640+tid]; }
      __syncthreads();
      float kn4[Rq], rstr[Rq];
      #pragma unroll
      for (int r=0;r<Rq;r++){
        float kk2=(tid<Wq)? xil[r*Wq+tid]*xil[r*Wq+tid] : 0.f;
        kn4[r]=sqrtf(blk_sum(kk2,s8));
        rstr[r]=oneplusf(xil[900+r]);
      }
      int n=tid;
      float wwn=wwl[n];
      float4* mrow=(float4*)(p.memv+((size_t)b*Nq+n)*Mq);
      const float4* er4=(const float4*)erl;
      const float4* wv4=(const float4*)wvl;
      const float4* k40=(const float4*)(xil);
      const float4* k41=(const float4*)(xil+128);
      const float4* k42=(const float4*)(xil+256);
      const float4* k43=(const float4*)(xil+384);
      float s=0.f,d0=0.f,d1=0.f,d2=0.f,d3=0.f;
      #pragma unroll 4
      for (int c=0;c<32;c++){
        float4 mv=mrow[c], e4=er4[c], w4=wv4[c];
        mv.x = mv.x*keep*(1.f-wwn*e4.x)+wwn*w4.x;
        mv.y = mv.y*keep*(1.f-wwn*e4.y)+wwn*w4.y;
        mv.z = mv.z*keep*(1.f-wwn*e4.z)+wwn*w4.z;
        mv.w = mv.w*keep*(1.f-wwn*e4.w)+wwn*w4.w;
        s+=dot4(mv,mv);
        d0+=dot4(k40[c],mv); d1+=dot4(k41[c],mv);
        d2+=dot4(k42[c],mv); d3+=dot4(k43[c],mv);
        mrow[c]=mv;
      }
      float mn=sqrtf(s);
      norms[n]=mn;
      float dd[4]={d0,d1,d2,d3};
      #pragma unroll
      for (int r=0;r<Rq;r++){
        float v=rstr[r]*(dd[r]/(kn4[r]*mn+1e-6f));
        float mx=blk_max(v,s8);
        float e=expf(v-mx);
        float se=blk_sum(e,s8);
        rcl[r*Nq+n]=e/se;
      }
    }
    team_bar(cnt, gen);  // B6
  } // t
}

// ---------- k_y: all outputs y[b][t][j] ----------
__global__ __launch_bounds__(512) void k_y(P p){
  int j=blockIdx.x, tid=threadIdx.x;
  __shared__ __align__(16) float wv[Wq];
  __shared__ __align__(16) float wr[Rq*Wq];
  if (tid<Wq) wv[tid]=p.WvT[(size_t)j*Wq+tid];
  wr[tid]=p.WrT[(size_t)j*(Rq*Wq)+tid];
  __syncthreads();
  int b=tid>>5, t=tid&31;
  const float4* h4=(const float4*)(p.out+BTWq+((size_t)b*Tq+t)*Wq);
  const float4* r4=(const float4*)(p.rdh+((size_t)b*Tq+t)*Nq);
  const float4* wv4=(const float4*)wv;
  const float4* wr4=(const float4*)wr;
  float a=0.f;
  #pragma unroll 8
  for (int c=0;c<32;c++) a+=dot4(wv4[c],h4[c]);
  #pragma unroll 8
  for (int c=0;c<128;c++) a+=dot4(wr4[c],r4[c]);
  p.out[((size_t)b*Tq+t)*Wq+j]=a+p.bv[j]+p.br[j];
}

extern "C" void kernel_launch(void* const* d_in, const int* in_sizes, int n_in,
                              void* d_out, int out_size, void* d_ws, size_t ws_size,
                              hipStream_t stream){
  (void)in_sizes; (void)n_in; (void)out_size; (void)ws_size;
  P p;
  p.X    = (const float*)d_in[0];
  p.hs0  = (const float*)d_in[1];
  p.mem0 = (const float*)d_in[2];
  p.rst  = (const int*)d_in[3];
  p.Wb   = (const float*)d_in[4];  p.bb   = (const float*)d_in[5];
  p.Wff1 = (const float*)d_in[6];  p.bff1 = (const float*)d_in[7];
  p.Wff2 = (const float*)d_in[8];  p.bff2 = (const float*)d_in[9];
  p.Wta  = (const float*)d_in[10]; p.bta  = (const float*)d_in[11];
  p.Wtb  = (const float*)d_in[12]; p.btb  = (const float*)d_in[13];
  p.Wv   = (const float*)d_in[14]; p.bv   = (const float*)d_in[15];
  p.Wr   = (const float*)d_in[16]; p.br   = (const float*)d_in[17];
  p.Wxi  = (const float*)d_in[18]; p.bxi  = (const float*)d_in[19];
  p.out  = (float*)d_out;
  float* ws = (float*)d_ws;
  size_t o = 0;
  p.link  = ws + o; o += (size_t)Bq*Nq*Nq;    // 4,194,304
  p.rdh   = ws + o; o += (size_t)Bq*Tq*Nq;    //   262,144
  p.memv  = ws + o; o += (size_t)Bq*Nq*Mq;    // 1,048,576
  p.teams = ws + o; o += (size_t)16*TSTRIDE;  //   393,216
  p.WbT   = ws + o; o += (size_t)DINq*Wq;
  p.Wff1T = ws + o; o += (size_t)Wq*Wq;
  p.Wff2T = ws + o; o += (size_t)Wq*Wq;
  p.WtaT  = ws + o; o += (size_t)Wq*Wq;
  p.WtbT  = ws + o; o += (size_t)Wq*Wq;
  p.WvT   = ws + o; o += (size_t)Wq*Wq;
  p.WrT   = ws + o; o += (size_t)Rq*Wq*Wq;
  p.WxiT  = ws + o; o += (size_t)XIDq*Wq;

  hipLaunchKernelGGL(k_init, dim3(38),  dim3(256), 0, stream, p);
  hipLaunchKernelGGL(k_run,  dim3(144), dim3(512), 0, stream, p);
  hipLaunchKernelGGL(k_y,    dim3(128), dim3(512), 0, stream, p);
}

// Round 7
// 4219.590 us; speedup vs baseline: 2.0041x; 1.0255x over previous
//
#include <hip/hip_runtime.h>
#include <math.h>

#define Bq 16
#define Tq 32
#define Wq 128
#define Rq 4
#define Nq 512
#define Mq 128
#define DINq 768
#define XIDq 919
#define BTWq (Bq*Tq*Wq)

// per-team payload arena (floats)
#define TSTRIDE 24576
#define TF_FW    0        // [8][4*512]
#define TF_BW    16384    // [4*512]
#define TF_RW    18432    // [4*512]
#define TF_WW    20480    // [512]
#define TF_PREC  20992    // [2][512] parity
#define TF_XI    22016    // [920]
#define TF_Z     22944    // [128]
#define TF_HS    23072    // [128]
#define TF_READS 23200    // [512]
#define TF_CNT   23712    // barrier counter (as unsigned)

struct P {
  const float *X, *hs0, *mem0;
  const int *rst;
  const float *Wb,*bb,*Wff1,*bff1,*Wff2,*bff2,*Wta,*bta,*Wtb,*btb,*Wv,*bv,*Wr,*br,*Wxi,*bxi;
  float *out;
  float *link,*rdh,*memv,*teams;
  float *WbT,*Wff1T,*Wff2T,*WtaT,*WtbT,*WvT,*WrT,*WxiT;
};

__device__ __forceinline__ float dot4(float4 a, float4 b){
  return a.x*b.x + a.y*b.y + a.z*b.z + a.w*b.w;
}
__device__ __forceinline__ float sigf(float x){ return 1.f/(1.f+expf(-x)); }
__device__ __forceinline__ float oneplusf(float x){ return 1.f + log1pf(expf(x) + 1e-6f); }

// coherent (agent-scope) payload access: per-access, no cache-wide maintenance
__device__ __forceinline__ void pst(float* p, float v){
  __hip_atomic_store(p, v, __ATOMIC_RELAXED, __HIP_MEMORY_SCOPE_AGENT);
}
__device__ __forceinline__ float pld(float* p){
  return __hip_atomic_load(p, __ATOMIC_RELAXED, __HIP_MEMORY_SCOPE_AGENT);
}

__device__ __forceinline__ void team_bar(unsigned* cnt, unsigned& gen){
  __syncthreads();                       // drains vmcnt: payload stores complete
  gen += 9;
  if (threadIdx.x==0){
    __hip_atomic_fetch_add(cnt, 1u, __ATOMIC_ACQ_REL, __HIP_MEMORY_SCOPE_AGENT);
    while (__hip_atomic_load(cnt, __ATOMIC_ACQUIRE, __HIP_MEMORY_SCOPE_AGENT) < gen)
      __builtin_amdgcn_s_sleep(1);
  }
  __syncthreads();
}

__device__ __forceinline__ float wave_sum64(float v){
  #pragma unroll
  for (int m=32;m>=1;m>>=1) v += __shfl_xor(v, m, 64);
  return v;
}
__device__ __forceinline__ float wave_max64(float v){
  #pragma unroll
  for (int m=32;m>=1;m>>=1) v = fmaxf(v, __shfl_xor(v, m, 64));
  return v;
}
__device__ __forceinline__ float blk_sum(float v, float* s8){
  int w = threadIdx.x>>6;
  v = wave_sum64(v);
  if ((threadIdx.x&63)==0) s8[w] = v;
  __syncthreads();
  float r = s8[0]+s8[1]+s8[2]+s8[3]+s8[4]+s8[5]+s8[6]+s8[7];
  __syncthreads();
  return r;
}
__device__ __forceinline__ float blk_max(float v, float* s8){
  int w = threadIdx.x>>6;
  v = wave_max64(v);
  if ((threadIdx.x&63)==0) s8[w] = v;
  __syncthreads();
  float r = s8[0];
  #pragma unroll
  for (int q=1;q<8;q++) r = fmaxf(r, s8[q]);
  __syncthreads();
  return r;
}

// ---------- k_init: weight transposes + zero team arenas ----------
__global__ __launch_bounds__(256) void k_init(P p){
  int bid=blockIdx.x, tid=threadIdx.x;
  if (bid<8){ int idx=bid*256+tid, st=8*256;
    for (int k=idx;k<DINq*Wq;k+=st){ int j=k/DINq,i=k%DINq; p.WbT[k]=p.Wb[i*Wq+j]; }
  } else if (bid<10){ int idx=(bid-8)*256+tid, st=2*256;
    for (int k=idx;k<Wq*Wq;k+=st){ int j=k/Wq,i=k%Wq; p.Wff1T[k]=p.Wff1[i*Wq+j]; }
  } else if (bid<12){ int idx=(bid-10)*256+tid, st=2*256;
    for (int k=idx;k<Wq*Wq;k+=st){ int j=k/Wq,i=k%Wq; p.Wff2T[k]=p.Wff2[i*Wq+j]; }
  } else if (bid<14){ int idx=(bid-12)*256+tid, st=2*256;
    for (int k=idx;k<Wq*Wq;k+=st){ int j=k/Wq,i=k%Wq; p.WtaT[k]=p.Wta[i*Wq+j]; }
  } else if (bid<16){ int idx=(bid-14)*256+tid, st=2*256;
    for (int k=idx;k<Wq*Wq;k+=st){ int j=k/Wq,i=k%Wq; p.WtbT[k]=p.Wtb[i*Wq+j]; }
  } else if (bid<18){ int idx=(bid-16)*256+tid, st=2*256;
    for (int k=idx;k<Wq*Wq;k+=st){ int j=k/Wq,i=k%Wq; p.WvT[k]=p.Wv[i*Wq+j]; }
  } else if (bid<22){ int idx=(bid-18)*256+tid, st=4*256;
    for (int k=idx;k<Rq*Wq*Wq;k+=st){ int j=k/(Rq*Wq),i=k%(Rq*Wq); p.WrT[k]=p.Wr[i*Wq+j]; }
  } else if (bid<30){ int idx=(bid-22)*256+tid, st=8*256;
    for (int k=idx;k<XIDq*Wq;k+=st){ int f=k/Wq,i=k%Wq; p.WxiT[k]=p.Wxi[i*XIDq+f]; }
  } else if (bid<38){ int idx=(bid-30)*256+tid, st=8*256;
    for (int k=idx;k<16*TSTRIDE;k+=st) p.teams[k]=0.f;
  }
}

// ---------- k_run: 16 teams x (1 alpha + 8 link blocks), whole scan ----------
// alpha blocks: bid 0..15 (team=bid)   -> XCD bid%8 (2 alphas/XCD)
// link  blocks: bid 16..143, team=(bid-16)>>3, g=(bid-16)&7 -> XCD == g%8:
//   all 16 teams' slice-g blocks share one XCD => per-XCD L2 holds
//   2MB link + ~180KB weight slice + 1MB memv (L2-resident, no HBM thrash).
__global__ __launch_bounds__(512) void k_run(P p){
  const int tid=threadIdx.x;
  const int bid=blockIdx.x;
  const bool isA = (bid<16);
  const int team = isA ? bid : ((bid-16)>>3);
  const int g    = isA ? 0   : ((bid-16)&7);
  const int b=team;
  float* T = p.teams + (size_t)team*TSTRIDE;
  unsigned* cnt = (unsigned*)(T + TF_CNT);
  unsigned gen = 0;

  __shared__ __align__(16) float rwl[Rq*Nq];
  __shared__ __align__(16) float rcl[Rq*Nq];
  __shared__ __align__(16) float xil[XIDq+9];
  __shared__ __align__(16) float inv[DINq];
  __shared__ __align__(16) float zll[Wq];
  __shared__ __align__(16) float hsl[Wq];
  __shared__ __align__(16) float wwl[Nq];
  __shared__ __align__(16) float precl[Nq];
  __shared__ __align__(16) float usage[Nq];
  __shared__ __align__(16) float wca[Nq];
  __shared__ __align__(16) float uarr[Nq];
  __shared__ __align__(16) float cpl[Nq];
  __shared__ __align__(16) float norms[Nq];
  __shared__ __align__(16) int   sidx[Nq];
  __shared__ __align__(16) float erl[Wq], wvl[Wq];
  __shared__ __align__(16) float fwacc[Rq*Nq];
  __shared__ float gacc[64];
  __shared__ float s8[8];

  // ---- init ----
  if (isA){
    for (int i=tid;i<Nq*Mq/4;i+=512)
      ((float4*)(p.memv+(size_t)b*Nq*Mq))[i] = ((const float4*)(p.mem0+(size_t)b*Nq*Mq))[i];
    for (int i=tid;i<Rq*Nq;i+=512){ rwl[i]=0.f; rcl[i]=0.f; }
    usage[tid]=0.f; precl[tid]=0.f; wwl[tid]=0.f;
    if (tid<Wq) pst(T+TF_HS+tid, p.hs0[b*Wq+tid]);
    __syncthreads();
    { int n=tid;
      const float4* mr=(const float4*)(p.memv+((size_t)b*Nq+n)*Mq);
      float s=0.f;
      #pragma unroll 8
      for (int c=0;c<32;c++) s+=dot4(mr[c],mr[c]);
      norms[n]=sqrtf(s);
    }
  } else {
    size_t base = ((size_t)b*Nq + (size_t)g*64)*Nq;
    float4* L = (float4*)(p.link + base);
    float4 z4 = make_float4(0.f,0.f,0.f,0.f);
    for (int i=tid;i<64*Nq/4;i+=512) L[i]=z4;
  }
  team_bar(cnt, gen);  // B0

  for (int t=0; t<=Tq; t++){
    // ---- ph1 (alpha): rw(t-1) combine + reads(t-1) ----
    if (isA){
      if (t>0){
        int n=tid;
        #pragma unroll
        for (int r=0;r<Rq;r++){
          float m0=xil[904+r*3], m1=xil[905+r*3], m2=xil[906+r*3];
          float mm=fmaxf(m0,fmaxf(m1,m2));
          float e0=expf(m0-mm), e1=expf(m1-mm), e2=expf(m2-mm);
          float es=e0+e1+e2;
          float fwv=0.f;
          #pragma unroll
          for (int gg=0;gg<8;gg++) fwv += pld(T+TF_FW+gg*2048+r*Nq+n);
          float bwv = pld(T+TF_BW+r*Nq+n);
          float rwv = (e0*bwv + e1*rcl[r*Nq+n] + e2*fwv)/es;
          rwl[r*Nq+n]=rwv;
          pst(T+TF_RW+r*Nq+n, rwv);
        }
        __syncthreads();
        int p4=tid>>7, m=tid&127;
        const float* rr_ = rwl + p4*Nq;
        const float* mb = p.memv + (size_t)b*Nq*Mq + m;
        float a0=0.f,a1=0.f,a2=0.f,a3=0.f;
        for (int n2=0;n2<Nq;n2+=4){
          a0+=rr_[n2+0]*mb[(size_t)(n2+0)*Mq];
          a1+=rr_[n2+1]*mb[(size_t)(n2+1)*Mq];
          a2+=rr_[n2+2]*mb[(size_t)(n2+2)*Mq];
          a3+=rr_[n2+3]*mb[(size_t)(n2+3)*Mq];
        }
        float a=(a0+a1)+(a2+a3);
        pst(T+TF_READS+tid, a);
        p.rdh[((size_t)b*Tq + (t-1))*Nq + tid] = a;
      } else {
        for (int i=tid;i<Rq*Nq;i+=512) pst(T+TF_RW+i, 0.f);
        pst(T+TF_READS+tid, 0.f);
      }
    }
    team_bar(cnt, gen);  // B1
    if (t==Tq) break;

    float keep = 1.f - (float)p.rst[b*Tq + t];
    // ---- ph2 (all): z-slice (alpha: j 0..15; link g: j 16+14g .. +13) ----
    for (int i=tid;i<DINq;i+=512){
      float v;
      if (i<Wq) v = p.X[((size_t)b*Tq+t)*Wq + i];
      else if (i<Wq+Nq) v = pld(T+TF_READS+i-Wq);
      else v = keep*pld(T+TF_HS+i-Wq-Nq);
      inv[i]=v;
    }
    __syncthreads();
    {
      int jj=tid>>5, q=tid&31;
      int j0 = isA ? 0 : (16 + g*14);
      int jn = isA ? 16 : 14;
      if (jj<jn){
        int j=j0+jj;
        const float4* w4=(const float4*)(p.WbT+(size_t)j*DINq);
        const float4* i4=(const float4*)inv;
        float a=0.f;
        #pragma unroll
        for (int kk=0;kk<6;kk++) a+=dot4(w4[q*6+kk], i4[q*6+kk]);
        #pragma unroll
        for (int m=1;m<32;m<<=1) a+=__shfl_xor(a,m,32);
        if (q==0){ a+=p.bb[j]; pst(T+TF_Z+j, a*sigf(a)); }
      }
    }
    team_bar(cnt, gen);  // B2
    // ---- ph3 (link): hs-slice, j = 16g .. 16g+15 ----
    if (!isA){
      if (tid<Wq) zll[tid]=pld(T+TF_Z+tid);
      __syncthreads();
      int jj=tid>>5, gate=(tid>>3)&3, q=tid&7;
      int j0=g*16;
      float a=0.f;
      {
        int j=j0+jj;
        const float* Wg = (gate==0)?p.Wff1T:(gate==1)?p.Wff2T:(gate==2)?p.WtaT:p.WtbT;
        const float4* w4=(const float4*)(Wg+(size_t)j*Wq);
        const float4* z4=(const float4*)zll;
        #pragma unroll
        for (int kk=0;kk<4;kk++) a+=dot4(w4[q*4+kk], z4[q*4+kk]);
        a+=__shfl_xor(a,1,8); a+=__shfl_xor(a,2,8); a+=__shfl_xor(a,4,8);
      }
      if (q==0) gacc[jj*4+gate]=a;
      __syncthreads();
      if (tid<16){
        int j=j0+tid;
        float a1=gacc[tid*4+0]+p.bff1[j], a2=gacc[tid*4+1]+p.bff2[j];
        float aa=gacc[tid*4+2]+p.bta[j],  ab=gacc[tid*4+3]+p.btb[j];
        float ti=sigf(aa*(float)t+ab);
        float h=a1*(1.f-ti)+ti*a2;
        pst(T+TF_HS+j, h);
        p.out[BTWq + ((size_t)b*Tq+t)*Wq + j] = h;
      }
    }
    team_bar(cnt, gen);  // B3
    // ---- ph4 (link): xi-slice, f = 115g .. ----
    if (!isA){
      if (tid<Wq) hsl[tid]=pld(T+TF_HS+tid);
      __syncthreads();
      int ff=tid>>2, q=tid&3;
      int f0=g*115, fn=(XIDq-f0<115)?(XIDq-f0):115;
      if (ff<fn){
        int f=f0+ff;
        const float4* w4=(const float4*)(p.WxiT+(size_t)f*Wq);
        const float4* h4=(const float4*)hsl;
        float a=0.f;
        #pragma unroll
        for (int kk=0;kk<8;kk++) a+=dot4(w4[q*8+kk], h4[q*8+kk]);
        a+=__shfl_xor(a,1,4); a+=__shfl_xor(a,2,4);
        if (q==0) pst(T+TF_XI+f, a+p.bxi[f]);
      }
    }
    team_bar(cnt, gen);  // B4
    // ---- ph5: alpha addr ; link prefetch rw/prec_old ----
    if (isA){
      for (int i=tid;i<XIDq;i+=512) xil[i]=pld(T+TF_XI+i);
      __syncthreads();
      float kk2 = (tid<Wq)? xil[512+tid]*xil[512+tid] : 0.f;
      float kn = sqrtf(blk_sum(kk2, s8));
      int n=tid;
      const float4* k4=(const float4*)(xil+512);
      const float4* mr=(const float4*)(p.memv+((size_t)b*Nq+n)*Mq);
      float d=0.f;
      #pragma unroll 8
      for (int c=0;c<32;c++) d+=dot4(k4[c],mr[c]);
      float mn=norms[n];
      float sim=(keep*d)/(kn*(keep*mn)+1e-6f);
      float wstr=oneplusf(xil[916]);
      float v=wstr*sim;
      float mx=blk_max(v,s8);
      float e=expf(v-mx);
      float se=blk_sum(e,s8);
      wca[n]=e/se;
      float ret=1.f;
      #pragma unroll
      for (int r=0;r<Rq;r++) ret *= 1.f - sigf(xil[896+r])*rwl[r*Nq+n];
      float uo=usage[n], pw=wwl[n];
      float u=(uo+pw-uo*pw)*ret;
      usage[n]=u; uarr[n]=u;
      __syncthreads();
      int rank=0;
      const float4* u4=(const float4*)uarr;
      #pragma unroll 8
      for (int jj=0;jj<128;jj++){
        float4 vv=u4[jj]; int j0=jj*4;
        rank += (vv.x<u)||(vv.x==u&&(j0+0)<n);
        rank += (vv.y<u)||(vv.y==u&&(j0+1)<n);
        rank += (vv.z<u)||(vv.z==u&&(j0+2)<n);
        rank += (vv.w<u)||(vv.w==u&&(j0+3)<n);
      }
      sidx[rank]=n;
      __syncthreads();
      int si=sidx[n];
      float sv=uarr[si];
      int w=tid>>6, l=tid&63;
      float x=sv;
      #pragma unroll
      for (int dd=1;dd<64;dd<<=1){
        float pr=__shfl_up(x,dd,64);
        if (l>=dd) x*=pr;
      }
      if (l==63) s8[w]=x;
      __syncthreads();
      float woff=1.f;
      #pragma unroll
      for (int q=0;q<8;q++) if (q<w) woff*=s8[q];
      x*=woff;
      cpl[n]=x;
      __syncthreads();
      float alloc=(1.f-u)*cpl[si];        // reference's cp[si[k]] indexing
      float ag=sigf(xil[917]), wg=sigf(xil[918]);
      float wwv=wg*(ag*alloc+(1.f-ag)*wca[n]);
      wwl[n]=wwv;
      pst(T+TF_WW+n, wwv);
      float wsum=blk_sum(wwv,s8);
      float pn=(1.f-wsum)*precl[n]+wwv;
      precl[n]=pn;
      pst(T+TF_PREC+(t&1)*Nq+n, pn);
    } else {
      for (int i=tid;i<Rq*Nq;i+=512) rwl[i]=pld(T+TF_RW+i);
      precl[tid]=pld(T+TF_PREC+((t&1)^1)*Nq+tid);
    }
    team_bar(cnt, gen);  // B5
    // ---- ph6 (link): link update + fw/bw ; (alpha): mem + norms + rca ----
    if (!isA){
      wwl[tid]=pld(T+TF_WW+tid);
      for (int i=tid;i<Rq*Nq;i+=512) fwacc[i]=0.f;
      __syncthreads();
      int w=tid>>6, l=tid&63, c0=l*8;
      float ww8[8], pc8[8], pr8[Rq][8];
      *(float4*)&ww8[0]=*(const float4*)&wwl[c0];   *(float4*)&ww8[4]=*(const float4*)&wwl[c0+4];
      *(float4*)&pc8[0]=*(const float4*)&precl[c0]; *(float4*)&pc8[4]=*(const float4*)&precl[c0+4];
      #pragma unroll
      for (int r=0;r<Rq;r++){
        *(float4*)&pr8[r][0]=*(const float4*)&rwl[r*Nq+c0];
        *(float4*)&pr8[r][4]=*(const float4*)&rwl[r*Nq+c0+4];
      }
      float fa[Rq][8];
      #pragma unroll
      for (int r=0;r<Rq;r++)
        #pragma unroll
        for (int q=0;q<8;q++) fa[r][q]=0.f;
      for (int rr=0;rr<8;rr++){
        int n = g*64 + w*8 + rr;
        float wwn = wwl[n];
        float prn[Rq];
        #pragma unroll
        for (int r=0;r<Rq;r++) prn[r]=rwl[r*Nq+n];
        size_t row = ((size_t)b*Nq+n)*Nq;
        float4 La=*(const float4*)(p.link+row+c0);
        float4 Lb=*(const float4*)(p.link+row+c0+4);
        float vv[8]={La.x,La.y,La.z,La.w,Lb.x,Lb.y,Lb.z,Lb.w};
        float bwp[Rq]={0.f,0.f,0.f,0.f};
        #pragma unroll
        for (int q=0;q<8;q++){
          float nv=(1.f-wwn-ww8[q])*vv[q]+wwn*pc8[q];
          if (c0+q==n) nv=0.f;
          vv[q]=nv;
          #pragma unroll
          for (int r=0;r<Rq;r++){ fa[r][q]+=prn[r]*nv; bwp[r]+=pr8[r][q]*nv; }
        }
        *(float4*)(p.link+row+c0)   = make_float4(vv[0],vv[1],vv[2],vv[3]);
        *(float4*)(p.link+row+c0+4) = make_float4(vv[4],vv[5],vv[6],vv[7]);
        #pragma unroll
        for (int mm=1;mm<64;mm<<=1)
          #pragma unroll
          for (int r=0;r<Rq;r++) bwp[r]+=__shfl_xor(bwp[r],mm,64);
        if (l==0){
          #pragma unroll
          for (int r=0;r<Rq;r++) pst(T+TF_BW+r*Nq+n, bwp[r]);
        }
      }
      #pragma unroll
      for (int r=0;r<Rq;r++)
        #pragma unroll
        for (int q=0;q<8;q++) atomicAdd(&fwacc[r*Nq+c0+q], fa[r][q]);
      __syncthreads();
      for (int i=tid;i<Rq*Nq;i+=512) pst(T+TF_FW+g*2048+i, fwacc[i]);
    } else {
      if (tid<Wq){ erl[tid]=sigf(xil[768+tid]); wvl[tid]=xil[640+tid]; }
      __syncthreads();
      float kn4[Rq], rstr[Rq];
      #pragma unroll
      for (int r=0;r<Rq;r++){
        float kk2=(tid<Wq)? xil[r*Wq+tid]*xil[r*Wq+tid] : 0.f;
        kn4[r]=sqrtf(blk_sum(kk2,s8));
        rstr[r]=oneplusf(xil[900+r]);
      }
      int n=tid;
      float wwn=wwl[n];
      float4* mrow=(float4*)(p.memv+((size_t)b*Nq+n)*Mq);
      const float4* er4=(const float4*)erl;
      const float4* wv4=(const float4*)wvl;
      const float4* k40=(const float4*)(xil);
      const float4* k41=(const float4*)(xil+128);
      const float4* k42=(const float4*)(xil+256);
      const float4* k43=(const float4*)(xil+384);
      float s=0.f,d0=0.f,d1=0.f,d2=0.f,d3=0.f;
      #pragma unroll 4
      for (int c=0;c<32;c++){
        float4 mv=mrow[c], e4=er4[c], w4=wv4[c];
        mv.x = mv.x*keep*(1.f-wwn*e4.x)+wwn*w4.x;
        mv.y = mv.y*keep*(1.f-wwn*e4.y)+wwn*w4.y;
        mv.z = mv.z*keep*(1.f-wwn*e4.z)+wwn*w4.z;
        mv.w = mv.w*keep*(1.f-wwn*e4.w)+wwn*w4.w;
        s+=dot4(mv,mv);
        d0+=dot4(k40[c],mv); d1+=dot4(k41[c],mv);
        d2+=dot4(k42[c],mv); d3+=dot4(k43[c],mv);
        mrow[c]=mv;
      }
      float mn=sqrtf(s);
      norms[n]=mn;
      float dd[4]={d0,d1,d2,d3};
      #pragma unroll
      for (int r=0;r<Rq;r++){
        float v=rstr[r]*(dd[r]/(kn4[r]*mn+1e-6f));
        float mx=blk_max(v,s8);
        float e=expf(v-mx);
        float se=blk_sum(e,s8);
        rcl[r*Nq+n]=e/se;
      }
    }
    team_bar(cnt, gen);  // B6
  } // t
}

// ---------- k_y: all outputs y[b][t][j] ----------
__global__ __launch_bounds__(512) void k_y(P p){
  int j=blockIdx.x, tid=threadIdx.x;
  __shared__ __align__(16) float wv[Wq];
  __shared__ __align__(16) float wr[Rq*Wq];
  if (tid<Wq) wv[tid]=p.WvT[(size_t)j*Wq+tid];
  wr[tid]=p.WrT[(size_t)j*(Rq*Wq)+tid];
  __syncthreads();
  int b=tid>>5, t=tid&31;
  const float4* h4=(const float4*)(p.out+BTWq+((size_t)b*Tq+t)*Wq);
  const float4* r4=(const float4*)(p.rdh+((size_t)b*Tq+t)*Nq);
  const float4* wv4=(const float4*)wv;
  const float4* wr4=(const float4*)wr;
  float a=0.f;
  #pragma unroll 8
  for (int c=0;c<32;c++) a+=dot4(wv4[c],h4[c]);
  #pragma unroll 8
  for (int c=0;c<128;c++) a+=dot4(wr4[c],r4[c]);
  p.out[((size_t)b*Tq+t)*Wq+j]=a+p.bv[j]+p.br[j];
}

extern "C" void kernel_launch(void* const* d_in, const int* in_sizes, int n_in,
                              void* d_out, int out_size, void* d_ws, size_t ws_size,
                              hipStream_t stream){
  (void)in_sizes; (void)n_in; (void)out_size; (void)ws_size;
  P p;
  p.X    = (const float*)d_in[0];
  p.hs0  = (const float*)d_in[1];
  p.mem0 = (const float*)d_in[2];
  p.rst  = (const int*)d_in[3];
  p.Wb   = (const float*)d_in[4];  p.bb   = (const float*)d_in[5];
  p.Wff1 = (const float*)d_in[6];  p.bff1 = (const float*)d_in[7];
  p.Wff2 = (const float*)d_in[8];  p.bff2 = (const float*)d_in[9];
  p.Wta  = (const float*)d_in[10]; p.bta  = (const float*)d_in[11];
  p.Wtb  = (const float*)d_in[12]; p.btb  = (const float*)d_in[13];
  p.Wv   = (const float*)d_in[14]; p.bv   = (const float*)d_in[15];
  p.Wr   = (const float*)d_in[16]; p.br   = (const float*)d_in[17];
  p.Wxi  = (const float*)d_in[18]; p.bxi  = (const float*)d_in[19];
  p.out  = (float*)d_out;
  float* ws = (float*)d_ws;
  size_t o = 0;
  p.link  = ws + o; o += (size_t)Bq*Nq*Nq;    // 4,194,304
  p.rdh   = ws + o; o += (size_t)Bq*Tq*Nq;    //   262,144
  p.memv  = ws + o; o += (size_t)Bq*Nq*Mq;    // 1,048,576
  p.teams = ws + o; o += (size_t)16*TSTRIDE;  //   393,216
  p.WbT   = ws + o; o += (size_t)DINq*Wq;
  p.Wff1T = ws + o; o += (size_t)Wq*Wq;
  p.Wff2T = ws + o; o += (size_t)Wq*Wq;
  p.WtaT  = ws + o; o += (size_t)Wq*Wq;
  p.WtbT  = ws + o; o += (size_t)Wq*Wq;
  p.WvT   = ws + o; o += (size_t)Wq*Wq;
  p.WrT   = ws + o; o += (size_t)Rq*Wq*Wq;
  p.WxiT  = ws + o; o += (size_t)XIDq*Wq;

  hipLaunchKernelGGL(k_init, dim3(38),  dim3(256), 0, stream, p);
  hipLaunchKernelGGL(k_run,  dim3(144), dim3(512), 0, stream, p);
  hipLaunchKernelGGL(k_y,    dim3(128), dim3(512), 0, stream, p);
}

// Round 8
// 3123.409 us; speedup vs baseline: 2.7075x; 1.3510x over previous
//
#include <hip/hip_runtime.h>
#include <math.h>

#define Bq 16
#define Tq 32
#define Wq 128
#define Rq 4
#define Nq 512
#define Mq 128
#define DINq 768
#define XIDq 919
#define BTWq (Bq*Tq*Wq)

// per-team payload arena (floats)
#define TSTRIDE 24576
#define TF_FW    0        // [8][4*512]
#define TF_BW    16384    // [4*512]
#define TF_RW    18432    // [4*512]
#define TF_WW    20480    // [512]
#define TF_PREC  20992    // [2][512] parity
#define TF_XI    22016    // [920]
#define TF_Z     22944    // [128]
#define TF_HS    23072    // [128]
#define TF_READS 23200    // [512]
#define TF_CNT   23712    // barrier counter (as unsigned)

struct P {
  const float *X, *hs0, *mem0;
  const int *rst;
  const float *Wb,*bb,*Wff1,*bff1,*Wff2,*bff2,*Wta,*bta,*Wtb,*btb,*Wv,*bv,*Wr,*br,*Wxi,*bxi;
  float *out;
  float *rdh,*memv,*teams;
  float *WbT,*Wff1T,*Wff2T,*WtaT,*WtbT,*WvT,*WrT,*WxiT;
};

__device__ __forceinline__ float dot4(float4 a, float4 b){
  return a.x*b.x + a.y*b.y + a.z*b.z + a.w*b.w;
}
__device__ __forceinline__ float sigf(float x){ return 1.f/(1.f+expf(-x)); }
__device__ __forceinline__ float oneplusf(float x){ return 1.f + log1pf(expf(x) + 1e-6f); }

// coherent (agent-scope, L1/L2-bypassing) payload access; RELAXED only —
// no acquire/release fences => no buffer_wbl2 / buffer_inv L2 flushes.
__device__ __forceinline__ void pst(float* p, float v){
  __hip_atomic_store(p, v, __ATOMIC_RELAXED, __HIP_MEMORY_SCOPE_AGENT);
}
__device__ __forceinline__ float pld(float* p){
  return __hip_atomic_load(p, __ATOMIC_RELAXED, __HIP_MEMORY_SCOPE_AGENT);
}

// team barrier: __syncthreads drains vmcnt(0) (payload stores are at the
// coherence point) before the counter bump; spin is relaxed (no cache inv).
__device__ __forceinline__ void team_bar(unsigned* cnt, unsigned& gen){
  __syncthreads();
  gen += 9;
  if (threadIdx.x==0){
    __hip_atomic_fetch_add(cnt, 1u, __ATOMIC_RELAXED, __HIP_MEMORY_SCOPE_AGENT);
    while (__hip_atomic_load(cnt, __ATOMIC_RELAXED, __HIP_MEMORY_SCOPE_AGENT) < gen)
      __builtin_amdgcn_s_sleep(2);
  }
  __syncthreads();
}

__device__ __forceinline__ float wave_sum64(float v){
  #pragma unroll
  for (int m=32;m>=1;m>>=1) v += __shfl_xor(v, m, 64);
  return v;
}
__device__ __forceinline__ float wave_max64(float v){
  #pragma unroll
  for (int m=32;m>=1;m>>=1) v = fmaxf(v, __shfl_xor(v, m, 64));
  return v;
}
__device__ __forceinline__ float blk_sum(float v, float* s8){
  int w = threadIdx.x>>6;
  v = wave_sum64(v);
  if ((threadIdx.x&63)==0) s8[w] = v;
  __syncthreads();
  float r = s8[0]+s8[1]+s8[2]+s8[3]+s8[4]+s8[5]+s8[6]+s8[7];
  __syncthreads();
  return r;
}
__device__ __forceinline__ float blk_max(float v, float* s8){
  int w = threadIdx.x>>6;
  v = wave_max64(v);
  if ((threadIdx.x&63)==0) s8[w] = v;
  __syncthreads();
  float r = s8[0];
  #pragma unroll
  for (int q=1;q<8;q++) r = fmaxf(r, s8[q]);
  __syncthreads();
  return r;
}

// ---------- k_init: weight transposes + zero team arenas ----------
__global__ __launch_bounds__(256) void k_init(P p){
  int bid=blockIdx.x, tid=threadIdx.x;
  if (bid<8){ int idx=bid*256+tid, st=8*256;
    for (int k=idx;k<DINq*Wq;k+=st){ int j=k/DINq,i=k%DINq; p.WbT[k]=p.Wb[i*Wq+j]; }
  } else if (bid<10){ int idx=(bid-8)*256+tid, st=2*256;
    for (int k=idx;k<Wq*Wq;k+=st){ int j=k/Wq,i=k%Wq; p.Wff1T[k]=p.Wff1[i*Wq+j]; }
  } else if (bid<12){ int idx=(bid-10)*256+tid, st=2*256;
    for (int k=idx;k<Wq*Wq;k+=st){ int j=k/Wq,i=k%Wq; p.Wff2T[k]=p.Wff2[i*Wq+j]; }
  } else if (bid<14){ int idx=(bid-12)*256+tid, st=2*256;
    for (int k=idx;k<Wq*Wq;k+=st){ int j=k/Wq,i=k%Wq; p.WtaT[k]=p.Wta[i*Wq+j]; }
  } else if (bid<16){ int idx=(bid-14)*256+tid, st=2*256;
    for (int k=idx;k<Wq*Wq;k+=st){ int j=k/Wq,i=k%Wq; p.WtbT[k]=p.Wtb[i*Wq+j]; }
  } else if (bid<18){ int idx=(bid-16)*256+tid, st=2*256;
    for (int k=idx;k<Wq*Wq;k+=st){ int j=k/Wq,i=k%Wq; p.WvT[k]=p.Wv[i*Wq+j]; }
  } else if (bid<22){ int idx=(bid-18)*256+tid, st=4*256;
    for (int k=idx;k<Rq*Wq*Wq;k+=st){ int j=k/(Rq*Wq),i=k%(Rq*Wq); p.WrT[k]=p.Wr[i*Wq+j]; }
  } else if (bid<30){ int idx=(bid-22)*256+tid, st=8*256;
    for (int k=idx;k<XIDq*Wq;k+=st){ int f=k/Wq,i=k%Wq; p.WxiT[k]=p.Wxi[i*XIDq+f]; }
  } else if (bid<38){ int idx=(bid-30)*256+tid, st=8*256;
    for (int k=idx;k<16*TSTRIDE;k+=st) p.teams[k]=0.f;
  }
}

// ---------- k_run: 16 teams x (1 alpha + 8 link blocks), whole scan ----------
// Link slice lives entirely in REGISTERS (Lreg[8][8] per thread): block-private
// across all 32 steps, zero memory traffic, immune to any cache maintenance.
__global__ __launch_bounds__(512) void k_run(P p){
  const int tid=threadIdx.x;
  const int bid=blockIdx.x;
  const bool isA = (bid<16);
  const int team = isA ? bid : ((bid-16)>>3);
  const int g    = isA ? 0   : ((bid-16)&7);
  const int b=team;
  float* T = p.teams + (size_t)team*TSTRIDE;
  unsigned* cnt = (unsigned*)(T + TF_CNT);
  unsigned gen = 0;

  // register-resident link slice: rows g*64 + (tid>>6)*8 + rr, cols (tid&63)*8 + q
  float Lreg[8][8];
  #pragma unroll
  for (int rr=0;rr<8;rr++)
    #pragma unroll
    for (int q=0;q<8;q++) Lreg[rr][q]=0.f;

  __shared__ __align__(16) float rwl[Rq*Nq];
  __shared__ __align__(16) float rcl[Rq*Nq];
  __shared__ __align__(16) float xil[XIDq+9];
  __shared__ __align__(16) float inv[DINq];
  __shared__ __align__(16) float zll[Wq];
  __shared__ __align__(16) float hsl[Wq];
  __shared__ __align__(16) float wwl[Nq];
  __shared__ __align__(16) float precl[Nq];
  __shared__ __align__(16) float usage[Nq];
  __shared__ __align__(16) float wca[Nq];
  __shared__ __align__(16) float uarr[Nq];
  __shared__ __align__(16) float cpl[Nq];
  __shared__ __align__(16) float norms[Nq];
  __shared__ __align__(16) int   sidx[Nq];
  __shared__ __align__(16) float erl[Wq], wvl[Wq];
  __shared__ __align__(16) float fwacc[Rq*Nq];
  __shared__ float gacc[64];
  __shared__ float s8[8];

  // ---- init ----
  if (isA){
    for (int i=tid;i<Nq*Mq/4;i+=512)
      ((float4*)(p.memv+(size_t)b*Nq*Mq))[i] = ((const float4*)(p.mem0+(size_t)b*Nq*Mq))[i];
    for (int i=tid;i<Rq*Nq;i+=512){ rwl[i]=0.f; rcl[i]=0.f; }
    usage[tid]=0.f; precl[tid]=0.f; wwl[tid]=0.f;
    if (tid<Wq) pst(T+TF_HS+tid, p.hs0[b*Wq+tid]);
    __syncthreads();
    { int n=tid;
      const float4* mr=(const float4*)(p.memv+((size_t)b*Nq+n)*Mq);
      float s=0.f;
      #pragma unroll 8
      for (int c=0;c<32;c++) s+=dot4(mr[c],mr[c]);
      norms[n]=sqrtf(s);
    }
  }
  team_bar(cnt, gen);  // B0

  for (int t=0; t<=Tq; t++){
    // ---- ph1 (alpha): rw(t-1) combine + reads(t-1) ----
    if (isA){
      if (t>0){
        int n=tid;
        #pragma unroll
        for (int r=0;r<Rq;r++){
          float m0=xil[904+r*3], m1=xil[905+r*3], m2=xil[906+r*3];
          float mm=fmaxf(m0,fmaxf(m1,m2));
          float e0=expf(m0-mm), e1=expf(m1-mm), e2=expf(m2-mm);
          float es=e0+e1+e2;
          float fwv=0.f;
          #pragma unroll
          for (int gg=0;gg<8;gg++) fwv += pld(T+TF_FW+gg*2048+r*Nq+n);
          float bwv = pld(T+TF_BW+r*Nq+n);
          float rwv = (e0*bwv + e1*rcl[r*Nq+n] + e2*fwv)/es;
          rwl[r*Nq+n]=rwv;
          pst(T+TF_RW+r*Nq+n, rwv);
        }
        __syncthreads();
        int p4=tid>>7, m=tid&127;
        const float* rr_ = rwl + p4*Nq;
        const float* mb = p.memv + (size_t)b*Nq*Mq + m;
        float a0=0.f,a1=0.f,a2=0.f,a3=0.f;
        for (int n2=0;n2<Nq;n2+=4){
          a0+=rr_[n2+0]*mb[(size_t)(n2+0)*Mq];
          a1+=rr_[n2+1]*mb[(size_t)(n2+1)*Mq];
          a2+=rr_[n2+2]*mb[(size_t)(n2+2)*Mq];
          a3+=rr_[n2+3]*mb[(size_t)(n2+3)*Mq];
        }
        float a=(a0+a1)+(a2+a3);
        pst(T+TF_READS+tid, a);
        p.rdh[((size_t)b*Tq + (t-1))*Nq + tid] = a;
      } else {
        for (int i=tid;i<Rq*Nq;i+=512) pst(T+TF_RW+i, 0.f);
        pst(T+TF_READS+tid, 0.f);
      }
    }
    team_bar(cnt, gen);  // B1
    if (t==Tq) break;

    float keep = 1.f - (float)p.rst[b*Tq + t];
    // ---- ph2 (all): z-slice (alpha: j 0..15; link g: j 16+14g .. +13) ----
    for (int i=tid;i<DINq;i+=512){
      float v;
      if (i<Wq) v = p.X[((size_t)b*Tq+t)*Wq + i];
      else if (i<Wq+Nq) v = pld(T+TF_READS+i-Wq);
      else v = keep*pld(T+TF_HS+i-Wq-Nq);
      inv[i]=v;
    }
    __syncthreads();
    {
      int jj=tid>>5, q=tid&31;
      int j0 = isA ? 0 : (16 + g*14);
      int jn = isA ? 16 : 14;
      if (jj<jn){
        int j=j0+jj;
        const float4* w4=(const float4*)(p.WbT+(size_t)j*DINq);
        const float4* i4=(const float4*)inv;
        float a=0.f;
        #pragma unroll
        for (int kk=0;kk<6;kk++) a+=dot4(w4[q*6+kk], i4[q*6+kk]);
        #pragma unroll
        for (int m=1;m<32;m<<=1) a+=__shfl_xor(a,m,32);
        if (q==0){ a+=p.bb[j]; pst(T+TF_Z+j, a*sigf(a)); }
      }
    }
    team_bar(cnt, gen);  // B2
    // ---- ph3 (link): hs-slice, j = 16g .. 16g+15 ----
    if (!isA){
      if (tid<Wq) zll[tid]=pld(T+TF_Z+tid);
      __syncthreads();
      int jj=tid>>5, gate=(tid>>3)&3, q=tid&7;
      int j0=g*16;
      float a=0.f;
      {
        int j=j0+jj;
        const float* Wg = (gate==0)?p.Wff1T:(gate==1)?p.Wff2T:(gate==2)?p.WtaT:p.WtbT;
        const float4* w4=(const float4*)(Wg+(size_t)j*Wq);
        const float4* z4=(const float4*)zll;
        #pragma unroll
        for (int kk=0;kk<4;kk++) a+=dot4(w4[q*4+kk], z4[q*4+kk]);
        a+=__shfl_xor(a,1,8); a+=__shfl_xor(a,2,8); a+=__shfl_xor(a,4,8);
      }
      if (q==0) gacc[jj*4+gate]=a;
      __syncthreads();
      if (tid<16){
        int j=j0+tid;
        float a1=gacc[tid*4+0]+p.bff1[j], a2=gacc[tid*4+1]+p.bff2[j];
        float aa=gacc[tid*4+2]+p.bta[j],  ab=gacc[tid*4+3]+p.btb[j];
        float ti=sigf(aa*(float)t+ab);
        float h=a1*(1.f-ti)+ti*a2;
        pst(T+TF_HS+j, h);
        p.out[BTWq + ((size_t)b*Tq+t)*Wq + j] = h;
      }
    }
    team_bar(cnt, gen);  // B3
    // ---- ph4 (link): xi-slice, f = 115g .. ----
    if (!isA){
      if (tid<Wq) hsl[tid]=pld(T+TF_HS+tid);
      __syncthreads();
      int ff=tid>>2, q=tid&3;
      int f0=g*115, fn=(XIDq-f0<115)?(XIDq-f0):115;
      if (ff<fn){
        int f=f0+ff;
        const float4* w4=(const float4*)(p.WxiT+(size_t)f*Wq);
        const float4* h4=(const float4*)hsl;
        float a=0.f;
        #pragma unroll
        for (int kk=0;kk<8;kk++) a+=dot4(w4[q*8+kk], h4[q*8+kk]);
        a+=__shfl_xor(a,1,4); a+=__shfl_xor(a,2,4);
        if (q==0) pst(T+TF_XI+f, a+p.bxi[f]);
      }
    }
    team_bar(cnt, gen);  // B4
    // ---- ph5: alpha addr ; link prefetch rw/prec_old ----
    if (isA){
      for (int i=tid;i<XIDq;i+=512) xil[i]=pld(T+TF_XI+i);
      __syncthreads();
      float kk2 = (tid<Wq)? xil[512+tid]*xil[512+tid] : 0.f;
      float kn = sqrtf(blk_sum(kk2, s8));
      int n=tid;
      const float4* k4=(const float4*)(xil+512);
      const float4* mr=(const float4*)(p.memv+((size_t)b*Nq+n)*Mq);
      float d=0.f;
      #pragma unroll 8
      for (int c=0;c<32;c++) d+=dot4(k4[c],mr[c]);
      float mn=norms[n];
      float sim=(keep*d)/(kn*(keep*mn)+1e-6f);
      float wstr=oneplusf(xil[916]);
      float v=wstr*sim;
      float mx=blk_max(v,s8);
      float e=expf(v-mx);
      float se=blk_sum(e,s8);
      wca[n]=e/se;
      float ret=1.f;
      #pragma unroll
      for (int r=0;r<Rq;r++) ret *= 1.f - sigf(xil[896+r])*rwl[r*Nq+n];
      float uo=usage[n], pw=wwl[n];
      float u=(uo+pw-uo*pw)*ret;
      usage[n]=u; uarr[n]=u;
      __syncthreads();
      int rank=0;
      const float4* u4=(const float4*)uarr;
      #pragma unroll 8
      for (int jj=0;jj<128;jj++){
        float4 vv=u4[jj]; int j0=jj*4;
        rank += (vv.x<u)||(vv.x==u&&(j0+0)<n);
        rank += (vv.y<u)||(vv.y==u&&(j0+1)<n);
        rank += (vv.z<u)||(vv.z==u&&(j0+2)<n);
        rank += (vv.w<u)||(vv.w==u&&(j0+3)<n);
      }
      sidx[rank]=n;
      __syncthreads();
      int si=sidx[n];
      float sv=uarr[si];
      int w=tid>>6, l=tid&63;
      float x=sv;
      #pragma unroll
      for (int dd=1;dd<64;dd<<=1){
        float pr=__shfl_up(x,dd,64);
        if (l>=dd) x*=pr;
      }
      if (l==63) s8[w]=x;
      __syncthreads();
      float woff=1.f;
      #pragma unroll
      for (int q=0;q<8;q++) if (q<w) woff*=s8[q];
      x*=woff;
      cpl[n]=x;
      __syncthreads();
      float alloc=(1.f-u)*cpl[si];        // reference's cp[si[k]] indexing
      float ag=sigf(xil[917]), wg=sigf(xil[918]);
      float wwv=wg*(ag*alloc+(1.f-ag)*wca[n]);
      wwl[n]=wwv;
      pst(T+TF_WW+n, wwv);
      float wsum=blk_sum(wwv,s8);
      float pn=(1.f-wsum)*precl[n]+wwv;
      precl[n]=pn;
      pst(T+TF_PREC+(t&1)*Nq+n, pn);
    } else {
      for (int i=tid;i<Rq*Nq;i+=512) rwl[i]=pld(T+TF_RW+i);
      precl[tid]=pld(T+TF_PREC+((t&1)^1)*Nq+tid);
    }
    team_bar(cnt, gen);  // B5
    // ---- ph6 (link): register-link update + fw/bw ; (alpha): mem + norms + rca ----
    if (!isA){
      wwl[tid]=pld(T+TF_WW+tid);
      for (int i=tid;i<Rq*Nq;i+=512) fwacc[i]=0.f;
      __syncthreads();
      int w=tid>>6, l=tid&63, c0=l*8;
      float ww8[8], pc8[8], pr8[Rq][8];
      *(float4*)&ww8[0]=*(const float4*)&wwl[c0];   *(float4*)&ww8[4]=*(const float4*)&wwl[c0+4];
      *(float4*)&pc8[0]=*(const float4*)&precl[c0]; *(float4*)&pc8[4]=*(const float4*)&precl[c0+4];
      #pragma unroll
      for (int r=0;r<Rq;r++){
        *(float4*)&pr8[r][0]=*(const float4*)&rwl[r*Nq+c0];
        *(float4*)&pr8[r][4]=*(const float4*)&rwl[r*Nq+c0+4];
      }
      float fa[Rq][8];
      #pragma unroll
      for (int r=0;r<Rq;r++)
        #pragma unroll
        for (int q=0;q<8;q++) fa[r][q]=0.f;
      #pragma unroll
      for (int rr=0;rr<8;rr++){
        int n = g*64 + w*8 + rr;
        float wwn = wwl[n];
        float prn[Rq];
        #pragma unroll
        for (int r=0;r<Rq;r++) prn[r]=rwl[r*Nq+n];
        float bwp[Rq]={0.f,0.f,0.f,0.f};
        #pragma unroll
        for (int q=0;q<8;q++){
          float nv=(1.f-wwn-ww8[q])*Lreg[rr][q]+wwn*pc8[q];
          if (c0+q==n) nv=0.f;
          Lreg[rr][q]=nv;
          #pragma unroll
          for (int r=0;r<Rq;r++){ fa[r][q]+=prn[r]*nv; bwp[r]+=pr8[r][q]*nv; }
        }
        #pragma unroll
        for (int mm=1;mm<64;mm<<=1)
          #pragma unroll
          for (int r=0;r<Rq;r++) bwp[r]+=__shfl_xor(bwp[r],mm,64);
        if (l==0){
          #pragma unroll
          for (int r=0;r<Rq;r++) pst(T+TF_BW+r*Nq+n, bwp[r]);
        }
      }
      #pragma unroll
      for (int r=0;r<Rq;r++)
        #pragma unroll
        for (int q=0;q<8;q++) atomicAdd(&fwacc[r*Nq+c0+q], fa[r][q]);
      __syncthreads();
      for (int i=tid;i<Rq*Nq;i+=512) pst(T+TF_FW+g*2048+i, fwacc[i]);
    } else {
      if (tid<Wq){ erl[tid]=sigf(xil[768+tid]); wvl[tid]=xil[640+tid]; }
      __syncthreads();
      float kn4[Rq], rstr[Rq];
      #pragma unroll
      for (int r=0;r<Rq;r++){
        float kk2=(tid<Wq)? xil[r*Wq+tid]*xil[r*Wq+tid] : 0.f;
        kn4[r]=sqrtf(blk_sum(kk2,s8));
        rstr[r]=oneplusf(xil[900+r]);
      }
      int n=tid;
      float wwn=wwl[n];
      float4* mrow=(float4*)(p.memv+((size_t)b*Nq+n)*Mq);
      const float4* er4=(const float4*)erl;
      const float4* wv4=(const float4*)wvl;
      const float4* k40=(const float4*)(xil);
      const float4* k41=(const float4*)(xil+128);
      const float4* k42=(const float4*)(xil+256);
      const float4* k43=(const float4*)(xil+384);
      float s=0.f,d0=0.f,d1=0.f,d2=0.f,d3=0.f;
      #pragma unroll 4
      for (int c=0;c<32;c++){
        float4 mv=mrow[c], e4=er4[c], w4=wv4[c];
        mv.x = mv.x*keep*(1.f-wwn*e4.x)+wwn*w4.x;
        mv.y = mv.y*keep*(1.f-wwn*e4.y)+wwn*w4.y;
        mv.z = mv.z*keep*(1.f-wwn*e4.z)+wwn*w4.z;
        mv.w = mv.w*keep*(1.f-wwn*e4.w)+wwn*w4.w;
        s+=dot4(mv,mv);
        d0+=dot4(k40[c],mv); d1+=dot4(k41[c],mv);
        d2+=dot4(k42[c],mv); d3+=dot4(k43[c],mv);
        mrow[c]=mv;
      }
      float mn=sqrtf(s);
      norms[n]=mn;
      float dd[4]={d0,d1,d2,d3};
      #pragma unroll
      for (int r=0;r<Rq;r++){
        float v=rstr[r]*(dd[r]/(kn4[r]*mn+1e-6f));
        float mx=blk_max(v,s8);
        float e=expf(v-mx);
        float se=blk_sum(e,s8);
        rcl[r*Nq+n]=e/se;
      }
    }
    team_bar(cnt, gen);  // B6
  } // t
}

// ---------- k_y: all outputs y[b][t][j] ----------
__global__ __launch_bounds__(512) void k_y(P p){
  int j=blockIdx.x, tid=threadIdx.x;
  __shared__ __align__(16) float wv[Wq];
  __shared__ __align__(16) float wr[Rq*Wq];
  if (tid<Wq) wv[tid]=p.WvT[(size_t)j*Wq+tid];
  wr[tid]=p.WrT[(size_t)j*(Rq*Wq)+tid];
  __syncthreads();
  int b=tid>>5, t=tid&31;
  const float4* h4=(const float4*)(p.out+BTWq+((size_t)b*Tq+t)*Wq);
  const float4* r4=(const float4*)(p.rdh+((size_t)b*Tq+t)*Nq);
  const float4* wv4=(const float4*)wv;
  const float4* wr4=(const float4*)wr;
  float a=0.f;
  #pragma unroll 8
  for (int c=0;c<32;c++) a+=dot4(wv4[c],h4[c]);
  #pragma unroll 8
  for (int c=0;c<128;c++) a+=dot4(wr4[c],r4[c]);
  p.out[((size_t)b*Tq+t)*Wq+j]=a+p.bv[j]+p.br[j];
}

extern "C" void kernel_launch(void* const* d_in, const int* in_sizes, int n_in,
                              void* d_out, int out_size, void* d_ws, size_t ws_size,
                              hipStream_t stream){
  (void)in_sizes; (void)n_in; (void)out_size; (void)ws_size;
  P p;
  p.X    = (const float*)d_in[0];
  p.hs0  = (const float*)d_in[1];
  p.mem0 = (const float*)d_in[2];
  p.rst  = (const int*)d_in[3];
  p.Wb   = (const float*)d_in[4];  p.bb   = (const float*)d_in[5];
  p.Wff1 = (const float*)d_in[6];  p.bff1 = (const float*)d_in[7];
  p.Wff2 = (const float*)d_in[8];  p.bff2 = (const float*)d_in[9];
  p.Wta  = (const float*)d_in[10]; p.bta  = (const float*)d_in[11];
  p.Wtb  = (const float*)d_in[12]; p.btb  = (const float*)d_in[13];
  p.Wv   = (const float*)d_in[14]; p.bv   = (const float*)d_in[15];
  p.Wr   = (const float*)d_in[16]; p.br   = (const float*)d_in[17];
  p.Wxi  = (const float*)d_in[18]; p.bxi  = (const float*)d_in[19];
  p.out  = (float*)d_out;
  float* ws = (float*)d_ws;
  size_t o = 0;
  p.rdh   = ws + o; o += (size_t)Bq*Tq*Nq;    //   262,144
  p.memv  = ws + o; o += (size_t)Bq*Nq*Mq;    // 1,048,576
  p.teams = ws + o; o += (size_t)16*TSTRIDE;  //   393,216
  p.WbT   = ws + o; o += (size_t)DINq*Wq;
  p.Wff1T = ws + o; o += (size_t)Wq*Wq;
  p.Wff2T = ws + o; o += (size_t)Wq*Wq;
  p.WtaT  = ws + o; o += (size_t)Wq*Wq;
  p.WtbT  = ws + o; o += (size_t)Wq*Wq;
  p.WvT   = ws + o; o += (size_t)Wq*Wq;
  p.WrT   = ws + o; o += (size_t)Rq*Wq*Wq;
  p.WxiT  = ws + o; o += (size_t)XIDq*Wq;

  hipLaunchKernelGGL(k_init, dim3(38),  dim3(256), 0, stream, p);
  hipLaunchKernelGGL(k_run,  dim3(144), dim3(512), 0, stream, p);
  hipLaunchKernelGGL(k_y,    dim3(128), dim3(512), 0, stream, p);
}

// Round 9
// 2720.247 us; speedup vs baseline: 3.1088x; 1.1482x over previous
//
#include <hip/hip_runtime.h>
#include <math.h>

#define Bq 16
#define Tq 32
#define Wq 128
#define Rq 4
#define Nq 512
#define Mq 128
#define DINq 768
#define XIDq 919
#define BTWq (Bq*Tq*Wq)

// per-team payload arena (floats)
#define TSTRIDE 24576
#define TF_FW    0        // [8][4*512]
#define TF_BW    16384    // [4*512]
#define TF_RW    18432    // [4*512]
#define TF_WW    20480    // [512]
#define TF_PREC  20992    // [2][512] parity
#define TF_XI    22016    // [920] (rows 0..511, 640..895 by link; alpha local rest)
#define TF_READS 23200    // [512]
#define TF_CNT   23712    // sync counters (unsigned), 64B-separated

struct P {
  const float *X, *hs0, *mem0;
  const int *rst;
  const float *Wb,*bb,*Wff1,*bff1,*Wff2,*bff2,*Wta,*bta,*Wtb,*btb,*Wv,*bv,*Wr,*br,*Wxi,*bxi;
  float *out;
  float *rdh,*memv,*teams;
  float *WbT,*Wff1T,*Wff2T,*WtaT,*WtbT,*WvT,*WrT,*WxiT;
};

__device__ __forceinline__ float dot4(float4 a, float4 b){
  return a.x*b.x + a.y*b.y + a.z*b.z + a.w*b.w;
}
__device__ __forceinline__ float sigf(float x){ return 1.f/(1.f+expf(-x)); }
__device__ __forceinline__ float oneplusf(float x){ return 1.f + log1pf(expf(x) + 1e-6f); }

// coherent (agent-scope, cache-bypassing) payload access; RELAXED only.
__device__ __forceinline__ void pst(float* p, float v){
  __hip_atomic_store(p, v, __ATOMIC_RELAXED, __HIP_MEMORY_SCOPE_AGENT);
}
__device__ __forceinline__ float pld(float* p){
  return __hip_atomic_load(p, __ATOMIC_RELAXED, __HIP_MEMORY_SCOPE_AGENT);
}
// producer: __syncthreads drains all threads' payload stores (vmcnt 0) first
__device__ __forceinline__ void bump(unsigned* f){
  __syncthreads();
  if (threadIdx.x==0)
    __hip_atomic_fetch_add(f, 1u, __ATOMIC_RELAXED, __HIP_MEMORY_SCOPE_AGENT);
}
__device__ __forceinline__ void setf(unsigned* f, unsigned v){
  __syncthreads();
  if (threadIdx.x==0)
    __hip_atomic_store(f, v, __ATOMIC_RELAXED, __HIP_MEMORY_SCOPE_AGENT);
}
// consumer: poll then block-sync
__device__ __forceinline__ void waitge(unsigned* f, unsigned v){
  if (threadIdx.x==0){
    while (__hip_atomic_load(f, __ATOMIC_RELAXED, __HIP_MEMORY_SCOPE_AGENT) < v)
      __builtin_amdgcn_s_sleep(1);
  }
  __syncthreads();
}

__device__ __forceinline__ float wave_sum64(float v){
  #pragma unroll
  for (int m=32;m>=1;m>>=1) v += __shfl_xor(v, m, 64);
  return v;
}
__device__ __forceinline__ float wave_max64(float v){
  #pragma unroll
  for (int m=32;m>=1;m>>=1) v = fmaxf(v, __shfl_xor(v, m, 64));
  return v;
}
__device__ __forceinline__ float blk_sum(float v, float* s8){
  int w = threadIdx.x>>6;
  v = wave_sum64(v);
  if ((threadIdx.x&63)==0) s8[w] = v;
  __syncthreads();
  float r = s8[0]+s8[1]+s8[2]+s8[3]+s8[4]+s8[5]+s8[6]+s8[7];
  __syncthreads();
  return r;
}
__device__ __forceinline__ float blk_max(float v, float* s8){
  int w = threadIdx.x>>6;
  v = wave_max64(v);
  if ((threadIdx.x&63)==0) s8[w] = v;
  __syncthreads();
  float r = s8[0];
  #pragma unroll
  for (int q=1;q<8;q++) r = fmaxf(r, s8[q]);
  __syncthreads();
  return r;
}

// ---------- k_init: weight transposes + zero team arenas ----------
__global__ __launch_bounds__(256) void k_init(P p){
  int bid=blockIdx.x, tid=threadIdx.x;
  if (bid<8){ int idx=bid*256+tid, st=8*256;
    for (int k=idx;k<DINq*Wq;k+=st){ int j=k/DINq,i=k%DINq; p.WbT[k]=p.Wb[i*Wq+j]; }
  } else if (bid<10){ int idx=(bid-8)*256+tid, st=2*256;
    for (int k=idx;k<Wq*Wq;k+=st){ int j=k/Wq,i=k%Wq; p.Wff1T[k]=p.Wff1[i*Wq+j]; }
  } else if (bid<12){ int idx=(bid-10)*256+tid, st=2*256;
    for (int k=idx;k<Wq*Wq;k+=st){ int j=k/Wq,i=k%Wq; p.Wff2T[k]=p.Wff2[i*Wq+j]; }
  } else if (bid<14){ int idx=(bid-12)*256+tid, st=2*256;
    for (int k=idx;k<Wq*Wq;k+=st){ int j=k/Wq,i=k%Wq; p.WtaT[k]=p.Wta[i*Wq+j]; }
  } else if (bid<16){ int idx=(bid-14)*256+tid, st=2*256;
    for (int k=idx;k<Wq*Wq;k+=st){ int j=k/Wq,i=k%Wq; p.WtbT[k]=p.Wtb[i*Wq+j]; }
  } else if (bid<18){ int idx=(bid-16)*256+tid, st=2*256;
    for (int k=idx;k<Wq*Wq;k+=st){ int j=k/Wq,i=k%Wq; p.WvT[k]=p.Wv[i*Wq+j]; }
  } else if (bid<22){ int idx=(bid-18)*256+tid, st=4*256;
    for (int k=idx;k<Rq*Wq*Wq;k+=st){ int j=k/(Rq*Wq),i=k%(Rq*Wq); p.WrT[k]=p.Wr[i*Wq+j]; }
  } else if (bid<30){ int idx=(bid-22)*256+tid, st=8*256;
    for (int k=idx;k<XIDq*Wq;k+=st){ int f=k/Wq,i=k%Wq; p.WxiT[k]=p.Wxi[i*XIDq+f]; }
  } else if (bid<38){ int idx=(bid-30)*256+tid, st=8*256;
    for (int k=idx;k<16*TSTRIDE;k+=st) p.teams[k]=0.f;
  }
}

// ---------- k_run: 16 teams x (1 alpha + 8 link blocks), flag-synced scan ----------
__global__ __launch_bounds__(512,2) void k_run(P p){
  const int tid=threadIdx.x, bid=blockIdx.x;
  const bool isA = (bid<16);
  const int team = isA ? bid : ((bid-16)>>3);
  const int g    = isA ? 0   : ((bid-16)&7);
  const int b=team;
  float* T = p.teams + (size_t)team*TSTRIDE;
  unsigned* C       = (unsigned*)(T + TF_CNT);
  unsigned* CNT_FW  = C + 0;
  unsigned* FLAG_RD = C + 32;
  unsigned* CNT_XI  = C + 64;
  unsigned* FLAG_WW = C + 96;

  __shared__ __align__(16) float inv[DINq];
  __shared__ __align__(16) float zl[Wq];
  __shared__ __align__(16) float hsl[Wq];
  __shared__ __align__(16) float acc4[4*Wq];
  __shared__ __align__(16) float rwl[Rq*Nq];
  __shared__ __align__(16) float rcl[Rq*Nq];
  __shared__ __align__(16) float key[Wq];
  __shared__ __align__(16) float keyv[Nq];
  __shared__ __align__(16) float xisc[32];
  __shared__ __align__(16) float wca[Nq];
  __shared__ __align__(16) float uarr[Nq];
  __shared__ __align__(16) float cpl[Nq];
  __shared__ __align__(16) float usage[Nq];
  __shared__ __align__(16) float wwl[Nq];
  __shared__ __align__(16) float precl[Nq];
  __shared__ __align__(16) float norms[Nq];
  __shared__ __align__(16) int   sidx[Nq];
  __shared__ __align__(16) float erl[Wq], wvl[Wq];
  __shared__ __align__(16) float fwacc[Rq*Nq];
  __shared__ float s8[8];

  if (isA){
    // ================= ALPHA =================
    for (int i=tid;i<Nq*Mq/4;i+=512)
      ((float4*)(p.memv+(size_t)b*Nq*Mq))[i] = ((const float4*)(p.mem0+(size_t)b*Nq*Mq))[i];
    for (int i=tid;i<Rq*Nq;i+=512){ rwl[i]=0.f; rcl[i]=0.f; }
    usage[tid]=0.f; precl[tid]=0.f; wwl[tid]=0.f;
    inv[Wq+tid]=0.f;                                 // reads(=0) slot for t=0
    if (tid<Wq) hsl[tid]=p.hs0[b*Wq+tid];
    __syncthreads();
    { int n=tid;
      const float4* mr=(const float4*)(p.memv+((size_t)b*Nq+n)*Mq);
      float s=0.f;
      #pragma unroll 8
      for (int c=0;c<32;c++) s+=dot4(mr[c],mr[c]);
      norms[n]=sqrtf(s);
    }

    for (int t=0; t<=Tq; t++){
      // ---- window1: rw(t-1) combine + reads(t-1) ----
      if (t>0){
        waitge(CNT_FW, 8u*(unsigned)t);              // links' ph6(t-1) done
        int n=tid;
        #pragma unroll
        for (int r=0;r<Rq;r++){
          float m0=xisc[8+r*3], m1=xisc[9+r*3], m2=xisc[10+r*3];
          float mm=fmaxf(m0,fmaxf(m1,m2));
          float e0=expf(m0-mm), e1=expf(m1-mm), e2=expf(m2-mm);
          float es=e0+e1+e2;
          float fwv=0.f;
          #pragma unroll
          for (int gg=0;gg<8;gg++) fwv += pld(T+TF_FW+gg*2048+r*Nq+n);
          float bwv = pld(T+TF_BW+r*Nq+n);
          float rwv = (e0*bwv + e1*rcl[r*Nq+n] + e2*fwv)/es;
          rwl[r*Nq+n]=rwv;
          pst(T+TF_RW+r*Nq+n, rwv);
        }
        __syncthreads();
        int p4=tid>>7, m=tid&127;
        const float* rr_ = rwl + p4*Nq;
        const float* mb = p.memv + (size_t)b*Nq*Mq + m;
        float a0=0.f,a1=0.f,a2=0.f,a3=0.f;
        for (int n2=0;n2<Nq;n2+=4){
          a0+=rr_[n2+0]*mb[(size_t)(n2+0)*Mq];
          a1+=rr_[n2+1]*mb[(size_t)(n2+1)*Mq];
          a2+=rr_[n2+2]*mb[(size_t)(n2+2)*Mq];
          a3+=rr_[n2+3]*mb[(size_t)(n2+3)*Mq];
        }
        float a=(a0+a1)+(a2+a3);
        inv[Wq+tid]=a;
        pst(T+TF_READS+tid, a);
        p.rdh[((size_t)b*Tq + (t-1))*Nq + tid] = a;
      }
      if (t==Tq) break;
      setf(FLAG_RD, (unsigned)(t+1));

      float keep = 1.f - (float)p.rst[b*Tq + t];
      // ---- window2: z, hs (redundant), own xi slice, addr ----
      if (tid<Wq){
        inv[tid] = p.X[((size_t)b*Tq+t)*Wq + tid];
        inv[Wq+Nq+tid] = keep*hsl[tid];
      }
      __syncthreads();
      { int j=tid>>2, q=tid&3;
        const float4* w4=(const float4*)(p.WbT+(size_t)j*DINq);
        const float4* i4=(const float4*)inv;
        float a=0.f;
        for (int c=q;c<192;c+=4) a+=dot4(w4[c], i4[c]);
        a+=__shfl_xor(a,1,4); a+=__shfl_xor(a,2,4);
        if (q==0){ a+=p.bb[j]; zl[j]=a*sigf(a); }
      }
      __syncthreads();
      { int which=tid>>7, j=tid&127;
        const float* Wg=(which==0)?p.Wff1T:(which==1)?p.Wff2T:(which==2)?p.WtaT:p.WtbT;
        const float4* w4=(const float4*)(Wg+(size_t)j*Wq);
        const float4* z4=(const float4*)zl;
        float a=0.f;
        #pragma unroll 8
        for (int c=0;c<32;c++) a+=dot4(w4[c], z4[c]);
        acc4[which*Wq+j]=a;
      }
      __syncthreads();
      if (tid<Wq){
        float a1=acc4[tid]+p.bff1[tid], a2=acc4[Wq+tid]+p.bff2[tid];
        float aa=acc4[2*Wq+tid]+p.bta[tid], ab=acc4[3*Wq+tid]+p.btb[tid];
        float ti=sigf(aa*(float)t+ab);
        float h=a1*(1.f-ti)+ti*a2;
        hsl[tid]=h;
        p.out[BTWq + ((size_t)b*Tq+t)*Wq + tid]=h;
      }
      __syncthreads();
      if (tid<151){                       // xi own slice: write_key + scalars
        int f=(tid<Wq)? (512+tid) : (896+(tid-Wq));
        const float4* w4=(const float4*)(p.WxiT+(size_t)f*Wq);
        const float4* h4=(const float4*)hsl;
        float a=p.bxi[f];
        #pragma unroll 8
        for (int c=0;c<32;c++) a+=dot4(w4[c], h4[c]);
        if (tid<Wq) key[tid]=a; else xisc[tid-Wq]=a;
      }
      __syncthreads();
      { // addr
        float kk2=(tid<Wq)? key[tid]*key[tid] : 0.f;
        float kn=sqrtf(blk_sum(kk2,s8));
        int n=tid;
        const float4* k4=(const float4*)key;
        const float4* mr=(const float4*)(p.memv+((size_t)b*Nq+n)*Mq);
        float d=0.f;
        #pragma unroll 8
        for (int c=0;c<32;c++) d+=dot4(k4[c],mr[c]);
        float mn=norms[n];
        float sim=(keep*d)/(kn*(keep*mn)+1e-6f);
        float wstr=oneplusf(xisc[20]);
        float v=wstr*sim;
        float mx=blk_max(v,s8);
        float e=expf(v-mx);
        float se=blk_sum(e,s8);
        wca[n]=e/se;
        float ret=1.f;
        #pragma unroll
        for (int r=0;r<Rq;r++) ret *= 1.f - sigf(xisc[r])*rwl[r*Nq+n];
        float uo=usage[n], pw=wwl[n];
        float u=(uo+pw-uo*pw)*ret;
        usage[n]=u; uarr[n]=u;
        __syncthreads();
        int rank=0;
        const float4* u4=(const float4*)uarr;
        #pragma unroll 8
        for (int jj=0;jj<128;jj++){
          float4 vv=u4[jj]; int j0=jj*4;
          rank += (vv.x<u)||(vv.x==u&&(j0+0)<n);
          rank += (vv.y<u)||(vv.y==u&&(j0+1)<n);
          rank += (vv.z<u)||(vv.z==u&&(j0+2)<n);
          rank += (vv.w<u)||(vv.w==u&&(j0+3)<n);
        }
        sidx[rank]=n;
        __syncthreads();
        int si=sidx[n];
        float sv=uarr[si];
        int w=tid>>6, l=tid&63;
        float x=sv;
        #pragma unroll
        for (int dd=1;dd<64;dd<<=1){
          float pr=__shfl_up(x,dd,64);
          if (l>=dd) x*=pr;
        }
        if (l==63) s8[w]=x;
        __syncthreads();
        float woff=1.f;
        #pragma unroll
        for (int q=0;q<8;q++) if (q<w) woff*=s8[q];
        x*=woff;
        cpl[n]=x;
        __syncthreads();
        float alloc=(1.f-u)*cpl[si];      // reference's cp[si[k]] indexing
        float ag=sigf(xisc[21]), wg=sigf(xisc[22]);
        float wwv=wg*(ag*alloc+(1.f-ag)*wca[n]);
        wwl[n]=wwv;
        pst(T+TF_WW+n, wwv);
        float wsum=blk_sum(wwv,s8);
        float pn=(1.f-wsum)*precl[n]+wwv;
        precl[n]=pn;
        pst(T+TF_PREC+(t&1)*Nq+n, pn);
      }
      setf(FLAG_WW, (unsigned)(t+1));

      // ---- window3: pld link xi rows, mem update + norms + rca ----
      waitge(CNT_XI, 8u*(unsigned)(t+1));
      for (int i=tid;i<768;i+=512){
        if (i<512)      keyv[i]      = pld(T+TF_XI+i);
        else if (i<640) wvl[i-512]   = pld(T+TF_XI+128+i);       // rows 640..767
        else            erl[i-640]   = sigf(pld(T+TF_XI+128+i)); // rows 768..895
      }
      __syncthreads();
      {
        float kn4[Rq], rstr[Rq];
        #pragma unroll
        for (int r=0;r<Rq;r++){
          float kk2=(tid<Wq)? keyv[r*Wq+tid]*keyv[r*Wq+tid] : 0.f;
          kn4[r]=sqrtf(blk_sum(kk2,s8));
          rstr[r]=oneplusf(xisc[4+r]);
        }
        int n=tid;
        float wwn=wwl[n];
        float4* mrow=(float4*)(p.memv+((size_t)b*Nq+n)*Mq);
        const float4* er4=(const float4*)erl;
        const float4* wv4=(const float4*)wvl;
        const float4* k40=(const float4*)(keyv);
        const float4* k41=(const float4*)(keyv+128);
        const float4* k42=(const float4*)(keyv+256);
        const float4* k43=(const float4*)(keyv+384);
        float s=0.f,d0=0.f,d1=0.f,d2=0.f,d3=0.f;
        #pragma unroll 4
        for (int c=0;c<32;c++){
          float4 mv=mrow[c], e4=er4[c], w4=wv4[c];
          mv.x = mv.x*keep*(1.f-wwn*e4.x)+wwn*w4.x;
          mv.y = mv.y*keep*(1.f-wwn*e4.y)+wwn*w4.y;
          mv.z = mv.z*keep*(1.f-wwn*e4.z)+wwn*w4.z;
          mv.w = mv.w*keep*(1.f-wwn*e4.w)+wwn*w4.w;
          s+=dot4(mv,mv);
          d0+=dot4(k40[c],mv); d1+=dot4(k41[c],mv);
          d2+=dot4(k42[c],mv); d3+=dot4(k43[c],mv);
          mrow[c]=mv;
        }
        float mn=sqrtf(s);
        norms[n]=mn;
        float dd[4]={d0,d1,d2,d3};
        #pragma unroll
        for (int r=0;r<Rq;r++){
          float v=rstr[r]*(dd[r]/(kn4[r]*mn+1e-6f));
          float mx=blk_max(v,s8);
          float e=expf(v-mx);
          float se=blk_sum(e,s8);
          rcl[r*Nq+n]=e/se;
        }
      }
    } // t loop (alpha)
  } else {
    // ================= LINK =================
    float Lreg[8][8];
    #pragma unroll
    for (int rr=0;rr<8;rr++)
      #pragma unroll
      for (int q=0;q<8;q++) Lreg[rr][q]=0.f;
    if (tid<Wq) hsl[tid]=p.hs0[b*Wq+tid];
    __syncthreads();

    for (int t=0; t<Tq; t++){
      waitge(FLAG_RD, (unsigned)(t+1));
      float keep = 1.f - (float)p.rst[b*Tq + t];
      // ---- z, hs redundant; xi slice pst ----
      inv[Wq+tid] = pld(T+TF_READS+tid);
      if (tid<Wq){
        inv[tid] = p.X[((size_t)b*Tq+t)*Wq + tid];
        inv[Wq+Nq+tid] = keep*hsl[tid];
      }
      __syncthreads();
      { int j=tid>>2, q=tid&3;
        const float4* w4=(const float4*)(p.WbT+(size_t)j*DINq);
        const float4* i4=(const float4*)inv;
        float a=0.f;
        for (int c=q;c<192;c+=4) a+=dot4(w4[c], i4[c]);
        a+=__shfl_xor(a,1,4); a+=__shfl_xor(a,2,4);
        if (q==0){ a+=p.bb[j]; zl[j]=a*sigf(a); }
      }
      __syncthreads();
      { int which=tid>>7, j=tid&127;
        const float* Wg=(which==0)?p.Wff1T:(which==1)?p.Wff2T:(which==2)?p.WtaT:p.WtbT;
        const float4* w4=(const float4*)(Wg+(size_t)j*Wq);
        const float4* z4=(const float4*)zl;
        float a=0.f;
        #pragma unroll 8
        for (int c=0;c<32;c++) a+=dot4(w4[c], z4[c]);
        acc4[which*Wq+j]=a;
      }
      __syncthreads();
      if (tid<Wq){
        float a1=acc4[tid]+p.bff1[tid], a2=acc4[Wq+tid]+p.bff2[tid];
        float aa=acc4[2*Wq+tid]+p.bta[tid], ab=acc4[3*Wq+tid]+p.btb[tid];
        float ti=sigf(aa*(float)t+ab);
        hsl[tid]=a1*(1.f-ti)+ti*a2;
      }
      __syncthreads();
      { int rr=tid>>2, q=tid&3;                 // xi slice g: 96 rows
        if (rr<96){
          int idx=g*96+rr;
          int f=(idx<512)? idx : (idx+128);
          const float4* w4=(const float4*)(p.WxiT+(size_t)f*Wq);
          const float4* h4=(const float4*)hsl;
          float a=0.f;
          #pragma unroll
          for (int kk=0;kk<8;kk++) a+=dot4(w4[q*8+kk], h4[q*8+kk]);
          a+=__shfl_xor(a,1,4); a+=__shfl_xor(a,2,4);
          if (q==0) pst(T+TF_XI+f, a+p.bxi[f]);
        }
      }
      bump(CNT_XI);
      // ---- prefetch rw + prec(old parity) ----
      for (int i=tid;i<Rq*Nq;i+=512) rwl[i]=pld(T+TF_RW+i);
      precl[tid]=pld(T+TF_PREC+((t&1)^1)*Nq+tid);
      waitge(FLAG_WW, (unsigned)(t+1));
      wwl[tid]=pld(T+TF_WW+tid);
      for (int i=tid;i<Rq*Nq;i+=512) fwacc[i]=0.f;
      __syncthreads();
      // ---- ph6: register-link update + fw/bw ----
      { int w=tid>>6, l=tid&63, c0=l*8;
        float ww8[8], pc8[8], pr8[Rq][8];
        *(float4*)&ww8[0]=*(const float4*)&wwl[c0];   *(float4*)&ww8[4]=*(const float4*)&wwl[c0+4];
        *(float4*)&pc8[0]=*(const float4*)&precl[c0]; *(float4*)&pc8[4]=*(const float4*)&precl[c0+4];
        #pragma unroll
        for (int r=0;r<Rq;r++){
          *(float4*)&pr8[r][0]=*(const float4*)&rwl[r*Nq+c0];
          *(float4*)&pr8[r][4]=*(const float4*)&rwl[r*Nq+c0+4];
        }
        float fa[Rq][8];
        #pragma unroll
        for (int r=0;r<Rq;r++)
          #pragma unroll
          for (int q=0;q<8;q++) fa[r][q]=0.f;
        #pragma unroll
        for (int rr=0;rr<8;rr++){
          int n = g*64 + w*8 + rr;
          float wwn = wwl[n];
          float prn[Rq];
          #pragma unroll
          for (int r=0;r<Rq;r++) prn[r]=rwl[r*Nq+n];
          float bwp[Rq]={0.f,0.f,0.f,0.f};
          #pragma unroll
          for (int q=0;q<8;q++){
            float nv=(1.f-wwn-ww8[q])*Lreg[rr][q]+wwn*pc8[q];
            if (c0+q==n) nv=0.f;
            Lreg[rr][q]=nv;
            #pragma unroll
            for (int r=0;r<Rq;r++){ fa[r][q]+=prn[r]*nv; bwp[r]+=pr8[r][q]*nv; }
          }
          #pragma unroll
          for (int mm=1;mm<64;mm<<=1)
            #pragma unroll
            for (int r=0;r<Rq;r++) bwp[r]+=__shfl_xor(bwp[r],mm,64);
          if (l==0){
            #pragma unroll
            for (int r=0;r<Rq;r++) pst(T+TF_BW+r*Nq+n, bwp[r]);
          }
        }
        #pragma unroll
        for (int r=0;r<Rq;r++)
          #pragma unroll
          for (int q=0;q<8;q++) atomicAdd(&fwacc[r*Nq+c0+q], fa[r][q]);
        __syncthreads();
        for (int i=tid;i<Rq*Nq;i+=512) pst(T+TF_FW+g*2048+i, fwacc[i]);
      }
      bump(CNT_FW);
    } // t loop (link)
  }
}

// ---------- k_y: all outputs y[b][t][j] ----------
__global__ __launch_bounds__(512) void k_y(P p){
  int j=blockIdx.x, tid=threadIdx.x;
  __shared__ __align__(16) float wv[Wq];
  __shared__ __align__(16) float wr[Rq*Wq];
  if (tid<Wq) wv[tid]=p.WvT[(size_t)j*Wq+tid];
  wr[tid]=p.WrT[(size_t)j*(Rq*Wq)+tid];
  __syncthreads();
  int b=tid>>5, t=tid&31;
  const float4* h4=(const float4*)(p.out+BTWq+((size_t)b*Tq+t)*Wq);
  const float4* r4=(const float4*)(p.rdh+((size_t)b*Tq+t)*Nq);
  const float4* wv4=(const float4*)wv;
  const float4* wr4=(const float4*)wr;
  float a=0.f;
  #pragma unroll 8
  for (int c=0;c<32;c++) a+=dot4(wv4[c],h4[c]);
  #pragma unroll 8
  for (int c=0;c<128;c++) a+=dot4(wr4[c],r4[c]);
  p.out[((size_t)b*Tq+t)*Wq+j]=a+p.bv[j]+p.br[j];
}

extern "C" void kernel_launch(void* const* d_in, const int* in_sizes, int n_in,
                              void* d_out, int out_size, void* d_ws, size_t ws_size,
                              hipStream_t stream){
  (void)in_sizes; (void)n_in; (void)out_size; (void)ws_size;
  P p;
  p.X    = (const float*)d_in[0];
  p.hs0  = (const float*)d_in[1];
  p.mem0 = (const float*)d_in[2];
  p.rst  = (const int*)d_in[3];
  p.Wb   = (const float*)d_in[4];  p.bb   = (const float*)d_in[5];
  p.Wff1 = (const float*)d_in[6];  p.bff1 = (const float*)d_in[7];
  p.Wff2 = (const float*)d_in[8];  p.bff2 = (const float*)d_in[9];
  p.Wta  = (const float*)d_in[10]; p.bta  = (const float*)d_in[11];
  p.Wtb  = (const float*)d_in[12]; p.btb  = (const float*)d_in[13];
  p.Wv   = (const float*)d_in[14]; p.bv   = (const float*)d_in[15];
  p.Wr   = (const float*)d_in[16]; p.br   = (const float*)d_in[17];
  p.Wxi  = (const float*)d_in[18]; p.bxi  = (const float*)d_in[19];
  p.out  = (float*)d_out;
  float* ws = (float*)d_ws;
  size_t o = 0;
  p.rdh   = ws + o; o += (size_t)Bq*Tq*Nq;    //   262,144
  p.memv  = ws + o; o += (size_t)Bq*Nq*Mq;    // 1,048,576
  p.teams = ws + o; o += (size_t)16*TSTRIDE;  //   393,216
  p.WbT   = ws + o; o += (size_t)DINq*Wq;
  p.Wff1T = ws + o; o += (size_t)Wq*Wq;
  p.Wff2T = ws + o; o += (size_t)Wq*Wq;
  p.WtaT  = ws + o; o += (size_t)Wq*Wq;
  p.WtbT  = ws + o; o += (size_t)Wq*Wq;
  p.WvT   = ws + o; o += (size_t)Wq*Wq;
  p.WrT   = ws + o; o += (size_t)Rq*Wq*Wq;
  p.WxiT  = ws + o; o += (size_t)XIDq*Wq;

  hipLaunchKernelGGL(k_init, dim3(38),  dim3(256), 0, stream, p);
  hipLaunchKernelGGL(k_run,  dim3(144), dim3(512), 0, stream, p);
  hipLaunchKernelGGL(k_y,    dim3(128), dim3(512), 0, stream, p);
}